// Round 18
// baseline (896.476 us; speedup 1.0000x reference)
//
#include <hip/hip_runtime.h>
#include <hip/hip_bf16.h>
#include <cmath>

typedef __hip_bfloat16 bf16;
typedef float f32x4 __attribute__((ext_vector_type(4)));
typedef int   i32x4 __attribute__((ext_vector_type(4)));

#define DEV static __device__ __forceinline__

constexpr int BB   = 4;
constexpr int SS   = 1024;
constexpr int DM   = 1024;
constexpr int HH   = 16;
constexpr int DHD  = 64;
constexpr int NEXP = 8;
constexpr int FFD  = 4096;
constexpr int NTOK = BB*SS;               // 4096
constexpr int CAP  = NTOK*2 + NEXP*128;   // 9216

DEV float bf2f(unsigned short u){ union{unsigned int i; float f;} z; z.i=((unsigned int)u)<<16; return z.f; }
DEV unsigned short f2bf(float f){ bf16 h = __float2bfloat16(f); return __builtin_bit_cast(unsigned short, h); }

DEV void stage16(const void* g, void* lds_base_uniform) {
  __builtin_amdgcn_global_load_lds(
      (const __attribute__((address_space(1))) void*)g,
      (__attribute__((address_space(3))) void*)lds_base_uniform,
      16, 0, 0);
}

// ---------------------------------------------------------------------------
// NT GEMM: C[M,N] = sum_p A_i[M,K] * B_j[N,K]^T. bf16 in, f32 acc.
// Double-buffered K-loop + XCD-bijective tile remap.
// NPASS=3: FUSED 2-term split (QKV): both planes per K-step, 3 MFMA combos.
// ---------------------------------------------------------------------------
template<int BM,int BN,int EPI,bool EXPERT,bool GATHER,bool OUT_SLOT,int NPASS=1,int ZMODE=0>
__global__ __launch_bounds__((BM/64)*(BN/64)*64)
void et_gemm(const bf16* __restrict__ A, const bf16* __restrict__ Bt, void* __restrict__ Cout,
             const float* __restrict__ bias, const float* __restrict__ res,
             int Kdim, int lda, int ldb, int ldc,
             long abs_, long bbs_, long cbs_, float scale,
             const int* __restrict__ pad_off, const int* __restrict__ slots,
             long psA, long psB, float* __restrict__ Cf, int bias_zs)
{
  constexpr int WN = BN/64, WM = BM/64, NW = WM*WN;
  constexpr int CA = (BM/16)/NW, CB = (BN/16)/NW;
  const int tid = threadIdx.x, wid = tid>>6, lane = tid&63;

  // ---- XCD-bijective tile remap ----
  const int gx = gridDim.x, gy = gridDim.y;
  const long nwg = (long)gx*gy*gridDim.z;
  long lin = blockIdx.x + (long)gx*(blockIdx.y + (long)gy*blockIdx.z);
  {
    const long q = nwg >> 3, r = nwg & 7;
    const long xcd = lin & 7, idx = lin >> 3;
    lin = (xcd < r ? xcd*(q+1) : r*(q+1) + (xcd-r)*q) + idx;
  }
  const int bxi = (int)(lin % gx);
  const long rem = lin / gx;
  const int byi = (int)(rem % gy);
  const int bzi = (int)(rem / gy);

  const int row0 = bxi*BM, col0 = byi*BN;
  const int z = bzi;
  int off0 = 0;
  if constexpr (EXPERT) {
    off0 = pad_off[z];
    const int rows = pad_off[z+1] - off0;
    if (row0 >= rows) return;
  }
  long coff;
  if constexpr (ZMODE==2) {
    A  += (long)z*SS*SS;
    Bt += (long)z*DHD*SS;
    coff = (long)(z>>4)*SS*DM + (long)(z&15)*64;
  } else {
    if constexpr (!EXPERT) A += (size_t)z * abs_;
    Bt += (size_t)z * bbs_;
    coff = (long)z*cbs_;
  }
  const long bofs = (long)z * bias_zs;

  const int sr = lane>>2;
  const int sk = (lane&3)*8;

  long arow[CA];
  #pragma unroll
  for (int i=0;i<CA;i++){
    const int r = (wid + i*NW)*16 + sr;
    if constexpr (GATHER)      arow[i] = slots[off0 + row0 + r];
    else if constexpr (EXPERT) arow[i] = off0 + row0 + r;
    else                       arow[i] = row0 + r;
  }
  int brow[CB];
  #pragma unroll
  for (int i=0;i<CB;i++) brow[i] = col0 + (wid + i*NW)*16 + sr;

  const int wm = wid / WN, wn = wid % WN;
  const int fr = lane & 15, fg = lane >> 4;

  f32x4 acc[4][4];
  #pragma unroll
  for (int m=0;m<4;m++)
    #pragma unroll
    for (int n=0;n<4;n++) acc[m][n] = (f32x4)(0.f);

  if constexpr (NPASS==3) {
    __shared__ __align__(16) bf16 As[2][2][BM*32];
    __shared__ __align__(16) bf16 Bs[2][2][BN*32];
    auto STG = [&](int buf, int kt) {
      #pragma unroll
      for (int i=0;i<CA;i++){
        stage16(A +        arow[i]*(long)lda + kt + sk, (void*)&As[buf][0][(wid + i*NW)*512]);
        stage16(A + psA +  arow[i]*(long)lda + kt + sk, (void*)&As[buf][1][(wid + i*NW)*512]);
      }
      #pragma unroll
      for (int i=0;i<CB;i++){
        stage16(Bt +       (long)brow[i]*ldb + kt + sk, (void*)&Bs[buf][0][(wid + i*NW)*512]);
        stage16(Bt + psB + (long)brow[i]*ldb + kt + sk, (void*)&Bs[buf][1][(wid + i*NW)*512]);
      }
    };
    const int nsteps = Kdim >> 5;
    int cur = 0;
    STG(0, 0);
    __syncthreads();
    for (int s = 0; s < nsteps; s++) {
      if (s + 1 < nsteps) STG(cur^1, (s+1)*32);
      i32x4 a0[4], a1[4], b0[4], b1[4];
      #pragma unroll
      for (int m=0;m<4;m++) {
        a0[m] = *(const i32x4*)&As[cur][0][(wm*64 + m*16 + fr)*32 + fg*8];
        a1[m] = *(const i32x4*)&As[cur][1][(wm*64 + m*16 + fr)*32 + fg*8];
      }
      #pragma unroll
      for (int n=0;n<4;n++) {
        b0[n] = *(const i32x4*)&Bs[cur][0][(wn*64 + n*16 + fr)*32 + fg*8];
        b1[n] = *(const i32x4*)&Bs[cur][1][(wn*64 + n*16 + fr)*32 + fg*8];
      }
      asm volatile("s_nop 1" ::);
      #pragma unroll
      for (int m=0;m<4;m++)
        #pragma unroll
        for (int n=0;n<4;n++) {
          asm("v_mfma_f32_16x16x32_bf16 %0, %1, %2, %0"
              : "+v"(acc[m][n]) : "v"(a0[m]), "v"(b0[n]));
          asm("v_mfma_f32_16x16x32_bf16 %0, %1, %2, %0"
              : "+v"(acc[m][n]) : "v"(a0[m]), "v"(b1[n]));
          asm("v_mfma_f32_16x16x32_bf16 %0, %1, %2, %0"
              : "+v"(acc[m][n]) : "v"(a1[m]), "v"(b0[n]));
        }
      __syncthreads();
      cur ^= 1;
    }
  } else {
    __shared__ __align__(16) bf16 As[2][BM*32];
    __shared__ __align__(16) bf16 Bs[2][BN*32];
    auto STAGE = [&](int buf, int kt) {
      #pragma unroll
      for (int i=0;i<CA;i++)
        stage16(A + arow[i]*(long)lda + kt + sk, (void*)&As[buf][(wid + i*NW)*512]);
      #pragma unroll
      for (int i=0;i<CB;i++)
        stage16(Bt + (long)brow[i]*ldb + kt + sk, (void*)&Bs[buf][(wid + i*NW)*512]);
    };
    const int nsteps = Kdim >> 5;
    int cur = 0;
    STAGE(0, 0);
    __syncthreads();
    for (int s = 0; s < nsteps; s++) {
      if (s + 1 < nsteps) STAGE(cur^1, (s+1)*32);
      i32x4 av[4], bv[4];
      #pragma unroll
      for (int m=0;m<4;m++) av[m] = *(const i32x4*)&As[cur][(wm*64 + m*16 + fr)*32 + fg*8];
      #pragma unroll
      for (int n=0;n<4;n++) bv[n] = *(const i32x4*)&Bs[cur][(wn*64 + n*16 + fr)*32 + fg*8];
      asm volatile("s_nop 1" ::);
      #pragma unroll
      for (int m=0;m<4;m++)
        #pragma unroll
        for (int n=0;n<4;n++)
          asm("v_mfma_f32_16x16x32_bf16 %0, %1, %2, %0"
              : "+v"(acc[m][n]) : "v"(av[m]), "v"(bv[n]));
      __syncthreads();
      cur ^= 1;
    }
  }

  #pragma unroll
  for (int m=0;m<4;m++)
    #pragma unroll
    for (int n=0;n<4;n++)
      asm volatile("s_nop 7\n\ts_nop 7" : "+v"(acc[m][n]) ::);

  const long rbase = (EXPERT && OUT_SLOT) ? (long)(off0 + row0) : (long)row0;
  #pragma unroll
  for (int m=0;m<4;m++) {
    #pragma unroll
    for (int n=0;n<4;n++) {
      #pragma unroll
      for (int j=0;j<4;j++) {
        const long r = rbase + wm*64 + m*16 + fg*4 + j;
        const long c = col0 + wn*64 + n*16 + fr;
        const size_t ci = (size_t)coff + (size_t)r*ldc + c;
        float v = acc[m][n][j];
        if constexpr (EPI==0) {
          ((bf16*)Cout)[ci] = __float2bfloat16(v + bias[bofs + c]);
        } else if constexpr (EPI==1) {
          ((bf16*)Cout)[ci] = __float2bfloat16(v*scale);
        } else if constexpr (EPI==2) {
          ((float*)Cout)[ci] = v + bias[bofs + c] + res[(size_t)r*ldc + c];
        } else if constexpr (EPI==3) {
          const float t = v + bias[bofs + c];
          ((bf16*)Cout)[ci] = __float2bfloat16(0.5f*t*(1.0f+erff(t*0.70710678118654752f)));
        } else {
          const float t = v + bias[bofs + c];
          ((bf16*)Cout)[ci] = __float2bfloat16(t);
          Cf[ci] = t;
        }
      }
    }
  }
}

// ---------------------------------------------------------------------------
// Fused flash attention, double-buffered K/V tiles.
// One block = 64 Q-rows of one (b,h); 4 waves x 16 Q-rows.
// ---------------------------------------------------------------------------
__global__ __launch_bounds__(256)
void k_flash(const bf16* __restrict__ qb, const bf16* __restrict__ kb,
             const bf16* __restrict__ vt, const int* __restrict__ mask,
             bf16* __restrict__ aob)
{
  const int qt = blockIdx.x, h = blockIdx.y, b = blockIdx.z;
  const int tid = threadIdx.x, wid = tid>>6, lane = tid&63;
  const int fr = lane & 15, fg = lane >> 4;
  __shared__ __align__(16) bf16 Ks[2][64*64];
  __shared__ __align__(16) bf16 Vs[2][64*64];
  __shared__ __align__(16) bf16 Pl[4][16*64];
  const int q0 = qt*64;
  const int qrow = q0 + wid*16 + fr;
  i32x4 qreg[2];
  #pragma unroll
  for (int c=0;c<2;c++)
    qreg[c] = *(const i32x4*)&qb[((size_t)(b*SS)+qrow)*DM + h*64 + c*32 + fg*8];
  f32x4 oacc[4];
  #pragma unroll
  for (int n=0;n<4;n++) oacc[n]=(f32x4)(0.f);
  float mrow[4], lrow[4];
  #pragma unroll
  for (int j=0;j<4;j++){ mrow[j]=-1e30f; lrow[j]=0.f; }

  const int srow = lane>>3;                 // 0..7 within 8-row chunk
  const int scolsw = ((lane&7) ^ srow)*8;   // pre-swizzled source column (elems)
  auto swz = [](int row, int coleb)->int {
    return row*128 + (coleb ^ ((row&7)<<4));
  };
  auto STAGE = [&](int buf, int kt) {
    const int kv0 = kt*64;
    #pragma unroll
    for (int i=0;i<2;i++) {
      const int r = (wid*2+i)*8 + srow;
      stage16(kb + ((size_t)(b*SS)+kv0+r)*DM + h*64 + scolsw, (void*)&Ks[buf][(wid*2+i)*512]);
      stage16(vt + ((size_t)(b*HH+h)*64 + r)*SS + kv0 + scolsw, (void*)&Vs[buf][(wid*2+i)*512]);
    }
  };

  const int NT = SS/64;
  int cur = 0;
  STAGE(0, 0);
  __syncthreads();
  for (int kt=0; kt<NT; kt++) {
    if (kt + 1 < NT) STAGE(cur^1, kt+1);
    const int kv0 = kt*64;
    // ---- QK^T ----
    f32x4 sacc[4];
    #pragma unroll
    for (int n=0;n<4;n++) sacc[n]=(f32x4)(0.f);
    asm volatile("s_nop 1" ::);
    #pragma unroll
    for (int c=0;c<2;c++) {
      i32x4 bk[4];
      #pragma unroll
      for (int n=0;n<4;n++)
        bk[n] = *(const i32x4*)((const char*)Ks[cur] + swz(n*16+fr, c*64+fg*16));
      #pragma unroll
      for (int n=0;n<4;n++)
        asm("v_mfma_f32_16x16x32_bf16 %0, %1, %2, %0"
            : "+v"(sacc[n]) : "v"(qreg[c]), "v"(bk[n]));
    }
    #pragma unroll
    for (int n=0;n<4;n++)
      asm volatile("s_nop 7\n\ts_nop 7" : "+v"(sacc[n]) ::);
    // ---- mask + scale ----
    float sc[4][4];
    #pragma unroll
    for (int n=0;n<4;n++) {
      const bool mm = mask[b*SS + kv0 + n*16 + fr] != 0;
      #pragma unroll
      for (int j=0;j<4;j++)
        sc[n][j] = mm ? sacc[n][j]*0.125f : -1e30f;
    }
    // ---- online softmax ----
    float scale[4];
    #pragma unroll
    for (int j=0;j<4;j++) {
      float tm = fmaxf(fmaxf(sc[0][j],sc[1][j]),fmaxf(sc[2][j],sc[3][j]));
      #pragma unroll
      for (int o=8;o;o>>=1) tm = fmaxf(tm, __shfl_xor(tm,o));
      const float nm = fmaxf(mrow[j], tm);
      scale[j] = __expf(mrow[j]-nm);
      mrow[j] = nm;
      float ts = 0.f;
      #pragma unroll
      for (int n=0;n<4;n++) { sc[n][j] = __expf(sc[n][j]-nm); ts += sc[n][j]; }
      #pragma unroll
      for (int o=8;o;o>>=1) ts += __shfl_xor(ts,o);
      lrow[j] = lrow[j]*scale[j] + ts;
    }
    // ---- rescale O ----
    #pragma unroll
    for (int n=0;n<4;n++)
      asm volatile("s_nop 7\n\ts_nop 7" : "+v"(oacc[n]) ::);
    #pragma unroll
    for (int n=0;n<4;n++)
      #pragma unroll
      for (int j=0;j<4;j++) oacc[n][j] *= scale[j];
    // ---- write P (swizzled, wave-local region) ----
    char* plw = (char*)Pl[wid];
    #pragma unroll
    for (int n=0;n<4;n++)
      #pragma unroll
      for (int j=0;j<4;j++) {
        const int row = fg*4+j, col = n*16+fr;
        *(bf16*)(plw + row*128 + ((col*2) ^ ((row&7)<<4))) = __float2bfloat16(sc[n][j]);
      }
    // ---- PV ----
    asm volatile("s_nop 1" ::);
    #pragma unroll
    for (int c=0;c<2;c++) {
      i32x4 pa = *(const i32x4*)(plw + swz(fr, c*64+fg*16));
      i32x4 bv[4];
      #pragma unroll
      for (int n=0;n<4;n++)
        bv[n] = *(const i32x4*)((const char*)Vs[cur] + swz(n*16+fr, c*64+fg*16));
      #pragma unroll
      for (int n=0;n<4;n++)
        asm("v_mfma_f32_16x16x32_bf16 %0, %1, %2, %0"
            : "+v"(oacc[n]) : "v"(pa), "v"(bv[n]));
    }
    __syncthreads();
    cur ^= 1;
  }
  #pragma unroll
  for (int n=0;n<4;n++)
    asm volatile("s_nop 7\n\ts_nop 7" : "+v"(oacc[n]) ::);
  #pragma unroll
  for (int j=0;j<4;j++) {
    const float ri = 1.0f / lrow[j];
    const size_t rbase = ((size_t)(b*SS) + q0 + wid*16 + fg*4 + j)*DM + h*64;
    #pragma unroll
    for (int n=0;n<4;n++)
      aob[rbase + n*16 + fr] = __float2bfloat16(oacc[n][j] * ri);
  }
}

// ---------------------------------------------------------------------------
// Transpose + convert to bf16, vectorized (weights)
// ---------------------------------------------------------------------------
template<typename T>
__global__ __launch_bounds__(256)
void et_transpose(const T* __restrict__ in, bf16* __restrict__ outp,
                  int ldin, int ldout, long in_bs, long out_bs)
{
  __shared__ float tile[64][65];
  const int z = blockIdx.z;
  in   += (size_t)z * in_bs;
  outp += (size_t)z * out_bs;
  const int r0 = blockIdx.x*64, c0 = blockIdx.y*64;
  const int tid = threadIdx.x;
  #pragma unroll
  for (int i=0;i<4;i++) {
    const int idx = tid*4 + i*1024;
    const int r = idx>>6, c = idx&63;
    if constexpr (sizeof(T)==4) {
      const float4 v = *(const float4*)&in[(size_t)(r0+r)*ldin + c0 + c];
      tile[r][c]=v.x; tile[r][c+1]=v.y; tile[r][c+2]=v.z; tile[r][c+3]=v.w;
    } else {
      const ushort4 v = *(const ushort4*)&in[(size_t)(r0+r)*ldin + c0 + c];
      tile[r][c]=bf2f(v.x); tile[r][c+1]=bf2f(v.y); tile[r][c+2]=bf2f(v.z); tile[r][c+3]=bf2f(v.w);
    }
  }
  __syncthreads();
  #pragma unroll
  for (int i=0;i<4;i++) {
    const int idx = tid*4 + i*1024;
    const int c = idx>>6, r = idx&63;
    ushort4 o;
    o.x=f2bf(tile[r][c]); o.y=f2bf(tile[r+1][c]); o.z=f2bf(tile[r+2][c]); o.w=f2bf(tile[r+3][c]);
    *(ushort4*)&outp[(size_t)(c0+c)*ldout + r0 + r] = o;
  }
}

// Merged expert weight transpose: z in [0,16): z<8 -> w1[e], else w2[e-8].
// Flattened 1024-tile x dimension.
__global__ __launch_bounds__(256)
void k_wtrans(const float* __restrict__ w1, const float* __restrict__ w2,
              bf16* __restrict__ w1Ta, bf16* __restrict__ w2Ta)
{
  __shared__ float tile[64][65];
  const int z = blockIdx.z;
  const int t = blockIdx.x;
  const float* in; bf16* outp; int ldin, ldout, r0, c0;
  const long EWS = (long)DM*FFD;
  if (z < 8) {         // w1[e]: [DM][FFD] -> w1Ta[e]: [FFD][DM]
    in = w1 + z*EWS; outp = w1Ta + z*EWS;
    ldin = FFD; ldout = DM;
    r0 = (t & 15)*64; c0 = (t >> 4)*64;    // r over DM(16 tiles), c over FFD(64)
  } else {             // w2[e]: [FFD][DM] -> w2Ta[e]: [DM][FFD]
    in = w2 + (z-8)*EWS; outp = w2Ta + (z-8)*EWS;
    ldin = DM; ldout = FFD;
    r0 = (t >> 4)*64; c0 = (t & 15)*64;    // r over FFD(64 tiles), c over DM(16)
  }
  const int tid = threadIdx.x;
  #pragma unroll
  for (int i=0;i<4;i++) {
    const int idx = tid*4 + i*1024;
    const int r = idx>>6, c = idx&63;
    const float4 v = *(const float4*)&in[(size_t)(r0+r)*ldin + c0 + c];
    tile[r][c]=v.x; tile[r][c+1]=v.y; tile[r][c+2]=v.z; tile[r][c+3]=v.w;
  }
  __syncthreads();
  #pragma unroll
  for (int i=0;i<4;i++) {
    const int idx = tid*4 + i*1024;
    const int c = idx>>6, r = idx&63;
    ushort4 o;
    o.x=f2bf(tile[r][c]); o.y=f2bf(tile[r+1][c]); o.z=f2bf(tile[r+2][c]); o.w=f2bf(tile[r+3][c]);
    *(ushort4*)&outp[(size_t)(c0+c)*ldout + r0 + r] = o;
  }
}

// Merged per-(b,h) head-slice transpose: z<64 -> V (bf16), else K (f32), zz=z-64.
__global__ __launch_bounds__(256)
void k_trans_head2(const bf16* __restrict__ vb, bf16* __restrict__ vt,
                   const float* __restrict__ kf, float* __restrict__ kfT)
{
  __shared__ float tile[64][65];
  const int z = blockIdx.z;
  const bool isV = (z < 64);
  const int zz = isV ? z : z - 64;
  const int r0 = blockIdx.x*64;
  const int tid = threadIdx.x;
  const size_t ibase = (size_t)(zz>>4)*SS*DM + (size_t)(zz&15)*64;
  #pragma unroll
  for (int i=0;i<4;i++) {
    const int idx = tid*4 + i*1024;
    const int r = idx>>6, c = idx&63;
    if (isV) {
      const ushort4 v = *(const ushort4*)&vb[ibase + (size_t)(r0+r)*DM + c];
      tile[r][c]=bf2f(v.x); tile[r][c+1]=bf2f(v.y); tile[r][c+2]=bf2f(v.z); tile[r][c+3]=bf2f(v.w);
    } else {
      const float4 v = *(const float4*)&kf[ibase + (size_t)(r0+r)*DM + c];
      tile[r][c]=v.x; tile[r][c+1]=v.y; tile[r][c+2]=v.z; tile[r][c+3]=v.w;
    }
  }
  __syncthreads();
  const size_t obase = (size_t)zz*DHD*SS;
  #pragma unroll
  for (int i=0;i<4;i++) {
    const int idx = tid*4 + i*1024;
    const int c = idx>>6, r = idx&63;
    if (isV) {
      ushort4 o;
      o.x=f2bf(tile[r][c]); o.y=f2bf(tile[r+1][c]); o.z=f2bf(tile[r+2][c]); o.w=f2bf(tile[r+3][c]);
      *(ushort4*)&vt[obase + (size_t)c*SS + r0 + r] = o;
    } else {
      float4 o;
      o.x=tile[r][c]; o.y=tile[r+1][c]; o.z=tile[r+2][c]; o.w=tile[r+3][c];
      *(float4*)&kfT[obase + (size_t)c*SS + r0 + r] = o;
    }
  }
}

// Transpose f32 -> 2-term split bf16 planes; z selects {wq,wk,wv}
__global__ __launch_bounds__(256)
void et_transpose2(const float* __restrict__ in0, const float* __restrict__ in1,
                   const float* __restrict__ in2, bf16* __restrict__ outp,
                   int ldin, int ldout, long pstride, long out_zs)
{
  __shared__ float tile[64][65];
  const int z = blockIdx.z;
  const float* in = (z==0) ? in0 : (z==1) ? in1 : in2;
  outp += (size_t)z * out_zs;
  const int r0 = blockIdx.x*64, c0 = blockIdx.y*64;
  const int tid = threadIdx.x;
  #pragma unroll
  for (int i=0;i<4;i++) {
    const int idx = tid*4 + i*1024;
    const int r = idx>>6, c = idx&63;
    const float4 v = *(const float4*)&in[(size_t)(r0+r)*ldin + c0 + c];
    tile[r][c]=v.x; tile[r][c+1]=v.y; tile[r][c+2]=v.z; tile[r][c+3]=v.w;
  }
  __syncthreads();
  #pragma unroll
  for (int i=0;i<4;i++) {
    const int idx = tid*4 + i*1024;
    const int c = idx>>6, r = idx&63;
    ushort4 o0, o1;
    unsigned short* p0 = (unsigned short*)&o0;
    unsigned short* p1 = (unsigned short*)&o1;
    #pragma unroll
    for (int j=0;j<4;j++) {
      float v = tile[r+j][c];
      const unsigned short h0 = f2bf(v);
      p0[j] = h0;
      v -= bf2f(h0);
      p1[j] = f2bf(v);
    }
    const size_t oi = (size_t)(c0+c)*ldout + r0 + r;
    *(ushort4*)&outp[oi] = o0;
    *(ushort4*)&outp[oi + pstride] = o1;
  }
}

// ---------------------------------------------------------------------------
// LayerNorm -> 2-term split bf16 planes (LN1)
// ---------------------------------------------------------------------------
__global__ __launch_bounds__(256)
void et_ln2(const float* __restrict__ xin, const float* __restrict__ g,
            const float* __restrict__ bsh, bf16* __restrict__ outp, long pstride)
{
  const int row = blockIdx.x, tid = threadIdx.x;
  const float4 v = ((const float4*)(xin + (size_t)row*DM))[tid];
  float s = v.x+v.y+v.z+v.w;
  #pragma unroll
  for (int o=32;o;o>>=1) s += __shfl_xor(s,o);
  __shared__ float s4[4], q4[4];
  if ((tid&63)==0) s4[tid>>6]=s;
  __syncthreads();
  const float mu = (s4[0]+s4[1]+s4[2]+s4[3]) * (1.f/DM);
  const float d0=v.x-mu,d1=v.y-mu,d2=v.z-mu,d3=v.w-mu;
  float q = d0*d0+d1*d1+d2*d2+d3*d3;
  #pragma unroll
  for (int o=32;o;o>>=1) q += __shfl_xor(q,o);
  if ((tid&63)==0) q4[tid>>6]=q;
  __syncthreads();
  const float var = (q4[0]+q4[1]+q4[2]+q4[3]) * (1.f/DM);
  const float rstd = rsqrtf(var + 1e-5f);
  const float4 gg = ((const float4*)g)[tid];
  const float4 bb = ((const float4*)bsh)[tid];
  float of[4];
  of[0] = d0*rstd*gg.x + bb.x;
  of[1] = d1*rstd*gg.y + bb.y;
  of[2] = d2*rstd*gg.z + bb.z;
  of[3] = d3*rstd*gg.w + bb.w;
  ushort4 p0, p1;
  unsigned short* pp0 = (unsigned short*)&p0;
  unsigned short* pp1 = (unsigned short*)&p1;
  #pragma unroll
  for (int k=0;k<4;k++) {
    float vv = of[k];
    const unsigned short h0 = f2bf(vv); pp0[k] = h0;
    vv -= bf2f(h0);
    pp1[k] = f2bf(vv);
  }
  const size_t oi = (size_t)row*DM;
  ((ushort4*)(outp + oi))[tid] = p0;
  ((ushort4*)(outp + pstride + oi))[tid] = p1;
}

// ---------------------------------------------------------------------------
// Router fused on x1: LN2 (f32) + write xn2 bf16 + logits + top-2 + provisional
// expert counts; flag near-ties into per-batch buckets.
// ---------------------------------------------------------------------------
__global__ __launch_bounds__(256)
void et_router2(const float* __restrict__ x1, const float* __restrict__ g,
                const float* __restrict__ bsh, const float* __restrict__ wr,
                const float* __restrict__ br, bf16* __restrict__ xn2,
                int* __restrict__ t2e, float* __restrict__ t2p,
                int* __restrict__ flaglist, int* __restrict__ cntb,
                int* __restrict__ cnt)
{
  const int wid = threadIdx.x>>6, lane = threadIdx.x&63;
  const int t = blockIdx.x*4 + wid;
  const float* xr = x1 + (size_t)t*DM;
  float4 xv[4];
  float s = 0.f;
  #pragma unroll
  for (int p=0;p<4;p++){
    xv[p] = *(const float4*)&xr[p*256 + lane*4];
    s += xv[p].x+xv[p].y+xv[p].z+xv[p].w;
  }
  #pragma unroll
  for (int o=32;o;o>>=1) s += __shfl_xor(s,o);
  const float mu = s * (1.f/DM);
  float q = 0.f;
  #pragma unroll
  for (int p=0;p<4;p++){
    const float a=xv[p].x-mu,b=xv[p].y-mu,c=xv[p].z-mu,d=xv[p].w-mu;
    q += a*a+b*b+c*c+d*d;
  }
  #pragma unroll
  for (int o=32;o;o>>=1) q += __shfl_xor(q,o);
  const float rstd = rsqrtf(q*(1.f/DM) + 1e-5f);
  float acc[NEXP];
  #pragma unroll
  for (int e=0;e<NEXP;e++) acc[e]=0.f;
  #pragma unroll
  for (int p=0;p<4;p++){
    const int d0 = p*256 + lane*4;
    const float4 gg = *(const float4*)&g[d0];
    const float4 bb = *(const float4*)&bsh[d0];
    float xn[4];
    xn[0]=(xv[p].x-mu)*rstd*gg.x+bb.x;
    xn[1]=(xv[p].y-mu)*rstd*gg.y+bb.y;
    xn[2]=(xv[p].z-mu)*rstd*gg.z+bb.z;
    xn[3]=(xv[p].w-mu)*rstd*gg.w+bb.w;
    ushort4 xo;
    xo.x=f2bf(xn[0]); xo.y=f2bf(xn[1]); xo.z=f2bf(xn[2]); xo.w=f2bf(xn[3]);
    *(ushort4*)&xn2[(size_t)t*DM + d0] = xo;
    #pragma unroll
    for (int j=0;j<4;j++){
      const float4 w0  = ((const float4*)&wr[(size_t)(d0+j)*NEXP])[0];
      const float4 w1v = ((const float4*)&wr[(size_t)(d0+j)*NEXP])[1];
      acc[0]+=xn[j]*w0.x;  acc[1]+=xn[j]*w0.y;  acc[2]+=xn[j]*w0.z;  acc[3]+=xn[j]*w0.w;
      acc[4]+=xn[j]*w1v.x; acc[5]+=xn[j]*w1v.y; acc[6]+=xn[j]*w1v.z; acc[7]+=xn[j]*w1v.w;
    }
  }
  #pragma unroll
  for (int e=0;e<NEXP;e++)
    #pragma unroll
    for (int o=32;o;o>>=1) acc[e] += __shfl_xor(acc[e],o);
  if (lane==0) {
    float v0=-1e30f, v1=-1e30f, v2=-1e30f; int e0=0, e1=0;
    #pragma unroll
    for (int e=0;e<NEXP;e++) {
      const float v = acc[e] + br[e];
      if (v>v0){v2=v1;v1=v0;e1=e0;v0=v;e0=e;}
      else if (v>v1){v2=v1;v1=v;e1=e;}
      else if (v>v2){v2=v;}
    }
    const float dd = __expf(v1-v0);
    const float p0 = 1.f/(1.f+dd);
    t2e[t*2]=e0; t2e[t*2+1]=e1;
    t2p[t*2]=p0; t2p[t*2+1]=dd*p0;
    atomicAdd(&cnt[e0], 1);
    atomicAdd(&cnt[e1], 1);
    if (v1 - v2 < 0.02f) {
      const int b = t >> 10;
      const int ib = atomicAdd(&cntb[b], 1);
      flaglist[b*1024 + ib] = t;
    }
  }
}

// ---------------------------------------------------------------------------
// Exact f32 attention recompute, 4 tokens per block iteration.
// ---------------------------------------------------------------------------
__global__ __launch_bounds__(256)
void k_rec4(const float* __restrict__ qf, const float* __restrict__ kfT,
            const float* __restrict__ vf, const int* __restrict__ flaglist,
            const int* __restrict__ cntb, const int* __restrict__ mask,
            float* __restrict__ aoF)
{
  const int h = blockIdx.y, b = blockIdx.z;
  const int tid = threadIdx.x, lane = tid&63, wv_ = tid>>6;
  const int nb = cntb[b];
  __shared__ float qs[4][64];
  __shared__ float scb[4][SS];
  __shared__ float part[4][4][64];
  __shared__ float tsum[4];
  const int* mrow = mask + (size_t)b*SS;
  const float* kbase = kfT + ((size_t)(b*HH + h)*DHD)*SS + tid;
  const float* vbase = vf + (size_t)b*SS*DM + h*64 + lane;

  for (int t0 = blockIdx.x*4; t0 < nb; t0 += gridDim.x*4) {
    const int nt = min(4, nb - t0);
    for (int idx = tid; idx < 4*64; idx += 256) {
      const int j = idx >> 6, d = idx & 63;
      float qv = 0.f;
      if (j < nt) {
        const int t = flaglist[b*1024 + t0 + j];
        qv = qf[(size_t)t*DM + h*64 + d];
      }
      qs[j][d] = qv;
    }
    __syncthreads();
    float a00=0,a01=0,a02=0,a03=0, a10=0,a11=0,a12=0,a13=0;
    float a20=0,a21=0,a22=0,a23=0, a30=0,a31=0,a32=0,a33=0;
    #pragma unroll 4
    for (int u=0; u<64; u++) {
      const float* kr = kbase + (size_t)u*SS;
      const float k0 = kr[0], k1 = kr[256], k2 = kr[512], k3 = kr[768];
      const float q0 = qs[0][u], q1 = qs[1][u], q2 = qs[2][u], q3 = qs[3][u];
      a00 += q0*k0; a01 += q0*k1; a02 += q0*k2; a03 += q0*k3;
      a10 += q1*k0; a11 += q1*k1; a12 += q1*k2; a13 += q1*k3;
      a20 += q2*k0; a21 += q2*k1; a22 += q2*k2; a23 += q2*k3;
      a30 += q3*k0; a31 += q3*k1; a32 += q3*k2; a33 += q3*k3;
    }
    const bool m0 = mrow[tid]!=0, m1 = mrow[tid+256]!=0, m2 = mrow[tid+512]!=0, m3 = mrow[tid+768]!=0;
    scb[0][tid]=m0?a00*0.125f:-1e30f; scb[0][tid+256]=m1?a01*0.125f:-1e30f;
    scb[0][tid+512]=m2?a02*0.125f:-1e30f; scb[0][tid+768]=m3?a03*0.125f:-1e30f;
    scb[1][tid]=m0?a10*0.125f:-1e30f; scb[1][tid+256]=m1?a11*0.125f:-1e30f;
    scb[1][tid+512]=m2?a12*0.125f:-1e30f; scb[1][tid+768]=m3?a13*0.125f:-1e30f;
    scb[2][tid]=m0?a20*0.125f:-1e30f; scb[2][tid+256]=m1?a21*0.125f:-1e30f;
    scb[2][tid+512]=m2?a22*0.125f:-1e30f; scb[2][tid+768]=m3?a23*0.125f:-1e30f;
    scb[3][tid]=m0?a30*0.125f:-1e30f; scb[3][tid+256]=m1?a31*0.125f:-1e30f;
    scb[3][tid+512]=m2?a32*0.125f:-1e30f; scb[3][tid+768]=m3?a33*0.125f:-1e30f;
    __syncthreads();
    {
      const int j = wv_;
      float v[16];
      float lm = -1e30f;
      #pragma unroll
      for (int kk=0;kk<16;kk++) { v[kk] = scb[j][lane + kk*64]; lm = fmaxf(lm, v[kk]); }
      #pragma unroll
      for (int o=32;o;o>>=1) lm = fmaxf(lm, __shfl_xor(lm,o));
      float ls = 0.f;
      #pragma unroll
      for (int kk=0;kk<16;kk++) {
        const float e = expf(v[kk]-lm);
        scb[j][lane + kk*64] = e; ls += e;
      }
      #pragma unroll
      for (int o=32;o;o>>=1) ls += __shfl_xor(ls,o);
      if (lane==0) tsum[j] = ls;
    }
    __syncthreads();
    float p0=0.f, p1=0.f, p2=0.f, p3=0.f;
    for (int s = wv_*4; s < SS; s += 16) {
      const float v0 = vbase[(size_t) s   *DM];
      const float v1 = vbase[(size_t)(s+1)*DM];
      const float v2 = vbase[(size_t)(s+2)*DM];
      const float v3 = vbase[(size_t)(s+3)*DM];
      p0 += scb[0][s]*v0 + scb[0][s+1]*v1 + scb[0][s+2]*v2 + scb[0][s+3]*v3;
      p1 += scb[1][s]*v0 + scb[1][s+1]*v1 + scb[1][s+2]*v2 + scb[1][s+3]*v3;
      p2 += scb[2][s]*v0 + scb[2][s+1]*v1 + scb[2][s+2]*v2 + scb[2][s+3]*v3;
      p3 += scb[3][s]*v0 + scb[3][s+1]*v1 + scb[3][s+2]*v2 + scb[3][s+3]*v3;
    }
    part[wv_][0][lane] = p0;
    part[wv_][1][lane] = p1;
    part[wv_][2][lane] = p2;
    part[wv_][3][lane] = p3;
    __syncthreads();
    for (int idx = tid; idx < nt*64; idx += 256) {
      const int j = idx >> 6, d = idx & 63;
      aoF[(size_t)(b*1024 + t0 + j)*DM + h*64 + d] =
        (part[0][j][d]+part[1][j][d]+part[2][j][d]+part[3][j][d]) / tsum[j];
    }
    __syncthreads();
  }
}

// ---------------------------------------------------------------------------
// Tiled flagged out-proj: 8 tokens x 128 cols per block; wo reuse x8.
// ---------------------------------------------------------------------------
__global__ __launch_bounds__(256)
void k_flag_proj2(const float* __restrict__ aoF, const float* __restrict__ wo,
                  const float* __restrict__ bo, const float* __restrict__ x,
                  const int* __restrict__ flaglist, const int* __restrict__ cntb,
                  float* __restrict__ yF)
{
  const int tile = blockIdx.x;
  const int b = tile >> 7;
  const int i0 = (tile & 127) * 8;
  const int nb = cntb[b];
  if (i0 >= nb) return;
  const int nt = min(8, nb - i0);
  const int c0 = blockIdx.y * 128;
  const int tid = threadIdx.x;
  const int c = c0 + (tid & 127);
  const int dh = tid >> 7;
  __shared__ float ar[8][DM];
  __shared__ float ph[2][8][128];
  for (int k = tid; k < 8*256; k += 256) {
    const int j = k >> 8, q4i = k & 255;
    float4 v = make_float4(0.f,0.f,0.f,0.f);
    if (j < nt) v = ((const float4*)(aoF + (size_t)(b*1024 + i0 + j)*DM))[q4i];
    ((float4*)ar[j])[q4i] = v;
  }
  __syncthreads();
  float acc0=0.f, acc1=0.f, acc2=0.f, acc3=0.f;
  float acc4=0.f, acc5=0.f, acc6=0.f, acc7=0.f;
  const int dbase = dh*512;
  #pragma unroll 4
  for (int d=0; d<512; d++) {
    const float w = wo[(size_t)(dbase+d)*DM + c];
    acc0 += ar[0][dbase+d]*w; acc1 += ar[1][dbase+d]*w;
    acc2 += ar[2][dbase+d]*w; acc3 += ar[3][dbase+d]*w;
    acc4 += ar[4][dbase+d]*w; acc5 += ar[5][dbase+d]*w;
    acc6 += ar[6][dbase+d]*w; acc7 += ar[7][dbase+d]*w;
  }
  const int lc = tid & 127;
  ph[dh][0][lc]=acc0; ph[dh][1][lc]=acc1; ph[dh][2][lc]=acc2; ph[dh][3][lc]=acc3;
  ph[dh][4][lc]=acc4; ph[dh][5][lc]=acc5; ph[dh][6][lc]=acc6; ph[dh][7][lc]=acc7;
  __syncthreads();
  for (int k = tid; k < nt*128; k += 256) {
    const int j = k >> 7, ccl = k & 127;
    const int cc = c0 + ccl;
    const int slot = b*1024 + i0 + j;
    const int t = flaglist[slot];
    yF[(size_t)slot*DM + cc] = ph[0][j][ccl] + ph[1][j][ccl] + bo[cc] + x[(size_t)t*DM + cc];
  }
}

// ---------------------------------------------------------------------------
// Flagged LN + router: overwrite t2e/t2p; adjust expert counts in-place.
// ---------------------------------------------------------------------------
__global__ __launch_bounds__(256)
void k_flag_router(const float* __restrict__ yF, const float* __restrict__ g,
                   const float* __restrict__ bsh, const float* __restrict__ wr,
                   const float* __restrict__ br, const int* __restrict__ flaglist,
                   const int* __restrict__ cntb, int* __restrict__ t2e,
                   float* __restrict__ t2p, int* __restrict__ cnt)
{
  const int tid = threadIdx.x, lane = tid&63, wv_ = tid>>6;
  __shared__ float s4[4], q4[4], pt[4][8];
  for (int idx = blockIdx.x; idx < NTOK; idx += gridDim.x) {
    const int b = idx >> 10, ib = idx & 1023;
    if (ib >= cntb[b]) continue;
    const int t = flaglist[idx];
    const float4 v = ((const float4*)(yF + (size_t)idx*DM))[tid];
    float s = v.x+v.y+v.z+v.w;
    #pragma unroll
    for (int o=32;o;o>>=1) s += __shfl_xor(s,o);
    if (lane==0) s4[wv_]=s;
    __syncthreads();
    const float mu = (s4[0]+s4[1]+s4[2]+s4[3])*(1.f/DM);
    const float d0=v.x-mu, d1=v.y-mu, d2=v.z-mu, d3=v.w-mu;
    float q = d0*d0+d1*d1+d2*d2+d3*d3;
    #pragma unroll
    for (int o=32;o;o>>=1) q += __shfl_xor(q,o);
    if (lane==0) q4[wv_]=q;
    __syncthreads();
    const float var = (q4[0]+q4[1]+q4[2]+q4[3])*(1.f/DM);
    const float rstd = 1.0f/sqrtf(var + 1e-5f);
    const int dbase = tid*4;
    const float4 gg = ((const float4*)g)[tid];
    const float4 bb = ((const float4*)bsh)[tid];
    const float x0 = d0*rstd*gg.x+bb.x, x1_ = d1*rstd*gg.y+bb.y;
    const float x2 = d2*rstd*gg.z+bb.z, x3_ = d3*rstd*gg.w+bb.w;
    float pl[8];
    #pragma unroll
    for (int e=0;e<8;e++)
      pl[e] = x0*wr[(size_t)(dbase+0)*8+e] + x1_*wr[(size_t)(dbase+1)*8+e]
            + x2*wr[(size_t)(dbase+2)*8+e] + x3_*wr[(size_t)(dbase+3)*8+e];
    #pragma unroll
    for (int e=0;e<8;e++)
      #pragma unroll
      for (int o=32;o;o>>=1) pl[e] += __shfl_xor(pl[e],o);
    if (lane==0) {
      #pragma unroll
      for (int e=0;e<8;e++) pt[wv_][e]=pl[e];
    }
    __syncthreads();
    if (tid==0) {
      float v0=-1e30f, v1=-1e30f; int e0=0, e1=0;
      for (int e=0;e<8;e++) {
        const float L = pt[0][e]+pt[1][e]+pt[2][e]+pt[3][e] + br[e];
        if (L>v0){v1=v0;e1=e0;v0=L;e0=e;}
        else if (L>v1){v1=L;e1=e;}
      }
      const float dd=expf(v1-v0), p0=1.f/(1.f+dd);
      const int oe0 = t2e[t*2], oe1 = t2e[t*2+1];
      if (oe0 != e0) { atomicSub(&cnt[oe0],1); atomicAdd(&cnt[e0],1); }
      if (oe1 != e1) { atomicSub(&cnt[oe1],1); atomicAdd(&cnt[e1],1); }
      t2e[t*2]=e0; t2e[t*2+1]=e1;
      t2p[t*2]=p0; t2p[t*2+1]=dd*p0;
    }
    __syncthreads();
  }
}

__global__ void et_init(const float* __restrict__ bq, const float* __restrict__ bk,
                        const float* __restrict__ bv, float* __restrict__ bcat,
                        int* __restrict__ cnt)
{
  const int i = blockIdx.x*256 + threadIdx.x;
  if (i < 16) cnt[i]=0;
  if (i < DM) { bcat[i]=bq[i]; bcat[DM+i]=bk[i]; bcat[2*DM+i]=bv[i]; }
}

__global__ void et_scan(const int* __restrict__ cnt, int* __restrict__ poff,
                        int* __restrict__ fil, int* __restrict__ slots)
{
  const int tid = threadIdx.x;
  if (tid==0) {
    int o=0;
    for (int e=0;e<NEXP;e++){ poff[e]=o; o += ((cnt[e]+127)>>7)<<7; }
    poff[NEXP]=o;
  }
  if (tid<NEXP) fil[tid]=0;
  for (int i=tid;i<CAP;i+=256) slots[i]=0;
}

__global__ void et_fill(const int* __restrict__ t2e, const int* __restrict__ poff,
                        int* __restrict__ fil, int* __restrict__ slots, int* __restrict__ sof)
{
  const int t = blockIdx.x*256 + threadIdx.x;
  if (t >= NTOK) return;
  #pragma unroll
  for (int kk=0;kk<2;kk++) {
    const int e = t2e[t*2+kk];
    const int pos = atomicAdd(&fil[e], 1);
    const int sl = poff[e] + pos;
    slots[sl] = t;
    sof[t*2+kk] = sl;
  }
}

__global__ __launch_bounds__(256)
void et_combine(const float* __restrict__ x1, const bf16* __restrict__ eo,
                const float* __restrict__ t2p, const int* __restrict__ sof,
                float* __restrict__ outp)
{
  const int t = blockIdx.x, tid = threadIdx.x;
  const int s0 = sof[t*2], s1 = sof[t*2+1];
  const float p0 = t2p[t*2], p1 = t2p[t*2+1];
  const float4 xv = ((const float4*)(x1 + (size_t)t*DM))[tid];
  const ushort4 a = ((const ushort4*)(eo + (size_t)s0*DM))[tid];
  const ushort4 c = ((const ushort4*)(eo + (size_t)s1*DM))[tid];
  float4 o;
  o.x = xv.x + p0*bf2f(a.x) + p1*bf2f(c.x);
  o.y = xv.y + p0*bf2f(a.y) + p1*bf2f(c.y);
  o.z = xv.z + p0*bf2f(a.z) + p1*bf2f(c.z);
  o.w = xv.w + p0*bf2f(a.w) + p1*bf2f(c.w);
  ((float4*)(outp + (size_t)t*DM))[tid] = o;
}

// ---------------------------------------------------------------------------
extern "C" void kernel_launch(void* const* d_in, const int* in_sizes, int n_in,
                              void* d_out, int out_size, void* d_ws, size_t ws_size,
                              hipStream_t stream)
{
  (void)in_sizes; (void)n_in; (void)out_size; (void)ws_size;
  const float* x    = (const float*)d_in[0];
  const int*   mask = (const int*)  d_in[1];
  const float* ln1g = (const float*)d_in[2];
  const float* ln1b = (const float*)d_in[3];
  const float* ln2g = (const float*)d_in[4];
  const float* ln2b = (const float*)d_in[5];
  const float* wq   = (const float*)d_in[6];
  const float* bq   = (const float*)d_in[7];
  const float* wk   = (const float*)d_in[8];
  const float* bk   = (const float*)d_in[9];
  const float* wv   = (const float*)d_in[10];
  const float* bv   = (const float*)d_in[11];
  const float* wo   = (const float*)d_in[12];
  const float* bo   = (const float*)d_in[13];
  const float* wr   = (const float*)d_in[14];
  const float* br   = (const float*)d_in[15];
  const float* w1   = (const float*)d_in[16];
  const float* b1   = (const float*)d_in[17];
  const float* w2   = (const float*)d_in[18];
  const float* b2   = (const float*)d_in[19];
  float* outp = (float*)d_out;

  char* wsb = (char*)d_ws;
  size_t off = 0;
  auto alloc = [&](size_t bytes)->void* {
    void* p = wsb + off;
    off += (bytes + 255) & ~(size_t)255;
    return p;
  };
  const long WPS  = (long)DM*DM;
  const long XPS  = (long)NTOK*DM;
  const long EWS  = (long)DM*FFD;
  bf16*  wqT2  = (bf16*) alloc((size_t)2*WPS*2);
  bf16*  wkT2  = (bf16*) alloc((size_t)2*WPS*2);
  bf16*  wvT2  = (bf16*) alloc((size_t)2*WPS*2);
  bf16*  woT   = (bf16*) alloc((size_t)WPS*2);
  bf16*  w1Ta  = (bf16*) alloc((size_t)NEXP*EWS*2);
  bf16*  w2Ta  = (bf16*) alloc((size_t)NEXP*EWS*2);
  bf16*  xn2p  = (bf16*) alloc((size_t)2*XPS*2);
  bf16*  qb    = (bf16*) alloc((size_t)XPS*2);
  bf16*  kb    = (bf16*) alloc((size_t)XPS*2);
  bf16*  vb    = (bf16*) alloc((size_t)XPS*2);
  bf16*  vt    = (bf16*) alloc((size_t)XPS*2);
  float* qf    = (float*)alloc((size_t)XPS*4);
  float* kf    = (float*)alloc((size_t)XPS*4);
  float* vf    = (float*)alloc((size_t)XPS*4);
  float* kfT   = (float*)alloc((size_t)XPS*4);
  bf16*  aob   = (bf16*) alloc((size_t)XPS*2);
  float* x1    = (float*)alloc((size_t)XPS*4);
  bf16*  xn2   = (bf16*) alloc((size_t)XPS*2);
  bf16*  hbuf  = (bf16*) alloc((size_t)CAP*FFD*2);
  bf16*  eo    = (bf16*) alloc((size_t)CAP*DM*2);
  float* bcat  = (float*)alloc((size_t)3*DM*4);
  int*   t2e   = (int*)  alloc((size_t)NTOK*2*4);
  float* t2p   = (float*)alloc((size_t)NTOK*2*4);
  int*   slots = (int*)  alloc((size_t)CAP*4);
  int*   sof   = (int*)  alloc((size_t)NTOK*2*4);
  int*   flagl = (int*)  alloc((size_t)NTOK*4);
  int*   cnt   = (int*)  alloc(64);
  int*   fil   = (int*)  alloc(64);
  int*   poff  = (int*)  alloc(64);
  int*   cntb  = cnt + 8;
  // Aliases (dead-buffer reuse):
  float* aoF   = (float*)qb;      // over qb+kb (dead after flash)
  float* yF    = (float*)vb;      // over vb+vt (dead after flash)

  const dim3 T256(256);

  et_init<<<4,T256,0,stream>>>(bq, bk, bv, bcat, cnt);
  et_transpose2<<<dim3(DM/64,DM/64,3),T256,0,stream>>>(wq, wk, wv, wqT2, DM, DM, WPS, 2*WPS);
  et_transpose<float><<<dim3(DM/64,DM/64,1),T256,0,stream>>>(wo, woT, DM, DM, 0, 0);

  et_ln2<<<NTOK,T256,0,stream>>>(x, ln1g, ln1b, xn2p, XPS);

  // QKV: fused 2-term split (both planes staged per K-step, 3 MFMA combos)
  et_gemm<128,64,4,false,false,false,3,0><<<dim3(NTOK/128, DM/64, 3),dim3(128),0,stream>>>(
      xn2p, wqT2, qb, bcat, nullptr, DM, DM, DM, DM,
      0, 2*WPS, XPS, 1.f, nullptr, nullptr, XPS, WPS, qf, DM);

  // merged head-slice transposes: z<64 -> V (bf16), z>=64 -> K (f32)
  k_trans_head2<<<dim3(SS/64,1,2*BB*HH),T256,0,stream>>>(vb, vt, kf, kfT);

  // fused flash attention (double-buffered K/V)
  k_flash<<<dim3(SS/64, HH, BB),T256,0,stream>>>(qb, kb, vt, mask, aob);

  // x1 = x + (ao @ wo + bo): 64x64 tiles -> 1024 blocks
  et_gemm<64,64,2,false,false,false,1,0><<<dim3(NTOK/64, DM/64, 1),dim3(64),0,stream>>>(
      aob, woT, x1, bo, x, DM, DM, DM, DM, 0,0,0, 1.f, nullptr,nullptr, 0,0,nullptr, 0);

  // router (fused LN2 + xn2 write + provisional counts)
  et_router2<<<NTOK/4,T256,0,stream>>>(x1, ln2g, ln2b, wr, br, xn2, t2e, t2p, flagl, cntb, cnt);
  k_rec4<<<dim3(32,HH,BB),T256,0,stream>>>(qf, kfT, vf, flagl, cntb, mask, aoF);
  k_flag_proj2<<<dim3(NTOK/8, DM/128),T256,0,stream>>>(aoF, wo, bo, x, flagl, cntb, yF);
  k_flag_router<<<1024,T256,0,stream>>>(yF, ln2g, ln2b, wr, br, flagl, cntb, t2e, t2p, cnt);

  et_scan<<<1,T256,0,stream>>>(cnt, poff, fil, slots);
  et_fill<<<NTOK/256,T256,0,stream>>>(t2e, poff, fil, slots, sof);

  // merged expert weight transposes (w1 + w2, z=16)
  k_wtrans<<<dim3(1024,1,16),T256,0,stream>>>(w1, w2, w1Ta, w2Ta);

  // FF1 / FF2: both 128x128 (verified best tile for B-panel reuse)
  et_gemm<128,128,3,true,true,true,1,0><<<dim3(NTOK/128, FFD/128, NEXP),T256,0,stream>>>(
      xn2, w1Ta, hbuf, b1, nullptr, DM, DM, DM, FFD,
      0, EWS, 0, 1.f, poff, slots, 0,0,nullptr, FFD);
  et_gemm<128,128,0,true,false,true,1,0><<<dim3(NTOK/128, DM/128, NEXP),T256,0,stream>>>(
      hbuf, w2Ta, eo, b2, nullptr, FFD, FFD, FFD, DM,
      0, EWS, 0, 1.f, poff, nullptr, 0,0,nullptr, DM);

  et_combine<<<NTOK,T256,0,stream>>>(x1, eo, t2p, sof, outp);
}

// Round 19
// 824.165 us; speedup vs baseline: 1.0877x; 1.0877x over previous
//
#include <hip/hip_runtime.h>
#include <hip/hip_bf16.h>
#include <cmath>

typedef __hip_bfloat16 bf16;
typedef float f32x4 __attribute__((ext_vector_type(4)));
typedef int   i32x4 __attribute__((ext_vector_type(4)));

#define DEV static __device__ __forceinline__

constexpr int BB   = 4;
constexpr int SS   = 1024;
constexpr int DM   = 1024;
constexpr int HH   = 16;
constexpr int DHD  = 64;
constexpr int NEXP = 8;
constexpr int FFD  = 4096;
constexpr int NTOK = BB*SS;               // 4096
constexpr int CAP  = NTOK*2 + NEXP*128;   // 9216

DEV float bf2f(unsigned short u){ union{unsigned int i; float f;} z; z.i=((unsigned int)u)<<16; return z.f; }
DEV unsigned short f2bf(float f){ bf16 h = __float2bfloat16(f); return __builtin_bit_cast(unsigned short, h); }

DEV void stage16(const void* g, void* lds_base_uniform) {
  __builtin_amdgcn_global_load_lds(
      (const __attribute__((address_space(1))) void*)g,
      (__attribute__((address_space(3))) void*)lds_base_uniform,
      16, 0, 0);
}

// ---------------------------------------------------------------------------
// NT GEMM: C[M,N] = sum_p A_i[M,K] * B_j[N,K]^T. bf16 in, f32 acc.
// Double-buffered K-loop + XCD-bijective tile remap.
// NPASS=3: FUSED 2-term split (QKV): both planes per K-step, 3 MFMA combos.
// ---------------------------------------------------------------------------
template<int BM,int BN,int EPI,bool EXPERT,bool GATHER,bool OUT_SLOT,int NPASS=1,int ZMODE=0>
__global__ __launch_bounds__((BM/64)*(BN/64)*64)
void et_gemm(const bf16* __restrict__ A, const bf16* __restrict__ Bt, void* __restrict__ Cout,
             const float* __restrict__ bias, const float* __restrict__ res,
             int Kdim, int lda, int ldb, int ldc,
             long abs_, long bbs_, long cbs_, float scale,
             const int* __restrict__ pad_off, const int* __restrict__ slots,
             long psA, long psB, float* __restrict__ Cf, int bias_zs)
{
  constexpr int WN = BN/64, WM = BM/64, NW = WM*WN;
  constexpr int CA = (BM/16)/NW, CB = (BN/16)/NW;
  const int tid = threadIdx.x, wid = tid>>6, lane = tid&63;

  // ---- XCD-bijective tile remap ----
  const int gx = gridDim.x, gy = gridDim.y;
  const long nwg = (long)gx*gy*gridDim.z;
  long lin = blockIdx.x + (long)gx*(blockIdx.y + (long)gy*blockIdx.z);
  {
    const long q = nwg >> 3, r = nwg & 7;
    const long xcd = lin & 7, idx = lin >> 3;
    lin = (xcd < r ? xcd*(q+1) : r*(q+1) + (xcd-r)*q) + idx;
  }
  const int bxi = (int)(lin % gx);
  const long rem = lin / gx;
  const int byi = (int)(rem % gy);
  const int bzi = (int)(rem / gy);

  const int row0 = bxi*BM, col0 = byi*BN;
  const int z = bzi;
  int off0 = 0;
  if constexpr (EXPERT) {
    off0 = pad_off[z];
    const int rows = pad_off[z+1] - off0;
    if (row0 >= rows) return;
  }
  long coff;
  if constexpr (ZMODE==2) {
    A  += (long)z*SS*SS;
    Bt += (long)z*DHD*SS;
    coff = (long)(z>>4)*SS*DM + (long)(z&15)*64;
  } else {
    if constexpr (!EXPERT) A += (size_t)z * abs_;
    Bt += (size_t)z * bbs_;
    coff = (long)z*cbs_;
  }
  const long bofs = (long)z * bias_zs;

  const int sr = lane>>2;
  const int sk = (lane&3)*8;

  long arow[CA];
  #pragma unroll
  for (int i=0;i<CA;i++){
    const int r = (wid + i*NW)*16 + sr;
    if constexpr (GATHER)      arow[i] = slots[off0 + row0 + r];
    else if constexpr (EXPERT) arow[i] = off0 + row0 + r;
    else                       arow[i] = row0 + r;
  }
  int brow[CB];
  #pragma unroll
  for (int i=0;i<CB;i++) brow[i] = col0 + (wid + i*NW)*16 + sr;

  const int wm = wid / WN, wn = wid % WN;
  const int fr = lane & 15, fg = lane >> 4;

  f32x4 acc[4][4];
  #pragma unroll
  for (int m=0;m<4;m++)
    #pragma unroll
    for (int n=0;n<4;n++) acc[m][n] = (f32x4)(0.f);

  if constexpr (NPASS==3) {
    __shared__ __align__(16) bf16 As[2][2][BM*32];
    __shared__ __align__(16) bf16 Bs[2][2][BN*32];
    auto STG = [&](int buf, int kt) {
      #pragma unroll
      for (int i=0;i<CA;i++){
        stage16(A +        arow[i]*(long)lda + kt + sk, (void*)&As[buf][0][(wid + i*NW)*512]);
        stage16(A + psA +  arow[i]*(long)lda + kt + sk, (void*)&As[buf][1][(wid + i*NW)*512]);
      }
      #pragma unroll
      for (int i=0;i<CB;i++){
        stage16(Bt +       (long)brow[i]*ldb + kt + sk, (void*)&Bs[buf][0][(wid + i*NW)*512]);
        stage16(Bt + psB + (long)brow[i]*ldb + kt + sk, (void*)&Bs[buf][1][(wid + i*NW)*512]);
      }
    };
    const int nsteps = Kdim >> 5;
    int cur = 0;
    STG(0, 0);
    __syncthreads();
    for (int s = 0; s < nsteps; s++) {
      if (s + 1 < nsteps) STG(cur^1, (s+1)*32);
      i32x4 a0[4], a1[4], b0[4], b1[4];
      #pragma unroll
      for (int m=0;m<4;m++) {
        a0[m] = *(const i32x4*)&As[cur][0][(wm*64 + m*16 + fr)*32 + fg*8];
        a1[m] = *(const i32x4*)&As[cur][1][(wm*64 + m*16 + fr)*32 + fg*8];
      }
      #pragma unroll
      for (int n=0;n<4;n++) {
        b0[n] = *(const i32x4*)&Bs[cur][0][(wn*64 + n*16 + fr)*32 + fg*8];
        b1[n] = *(const i32x4*)&Bs[cur][1][(wn*64 + n*16 + fr)*32 + fg*8];
      }
      asm volatile("s_nop 1" ::);
      #pragma unroll
      for (int m=0;m<4;m++)
        #pragma unroll
        for (int n=0;n<4;n++) {
          asm("v_mfma_f32_16x16x32_bf16 %0, %1, %2, %0"
              : "+v"(acc[m][n]) : "v"(a0[m]), "v"(b0[n]));
          asm("v_mfma_f32_16x16x32_bf16 %0, %1, %2, %0"
              : "+v"(acc[m][n]) : "v"(a0[m]), "v"(b1[n]));
          asm("v_mfma_f32_16x16x32_bf16 %0, %1, %2, %0"
              : "+v"(acc[m][n]) : "v"(a1[m]), "v"(b0[n]));
        }
      __syncthreads();
      cur ^= 1;
    }
  } else {
    __shared__ __align__(16) bf16 As[2][BM*32];
    __shared__ __align__(16) bf16 Bs[2][BN*32];
    auto STAGE = [&](int buf, int kt) {
      #pragma unroll
      for (int i=0;i<CA;i++)
        stage16(A + arow[i]*(long)lda + kt + sk, (void*)&As[buf][(wid + i*NW)*512]);
      #pragma unroll
      for (int i=0;i<CB;i++)
        stage16(Bt + (long)brow[i]*ldb + kt + sk, (void*)&Bs[buf][(wid + i*NW)*512]);
    };
    const int nsteps = Kdim >> 5;
    int cur = 0;
    STAGE(0, 0);
    __syncthreads();
    for (int s = 0; s < nsteps; s++) {
      if (s + 1 < nsteps) STAGE(cur^1, (s+1)*32);
      i32x4 av[4], bv[4];
      #pragma unroll
      for (int m=0;m<4;m++) av[m] = *(const i32x4*)&As[cur][(wm*64 + m*16 + fr)*32 + fg*8];
      #pragma unroll
      for (int n=0;n<4;n++) bv[n] = *(const i32x4*)&Bs[cur][(wn*64 + n*16 + fr)*32 + fg*8];
      asm volatile("s_nop 1" ::);
      #pragma unroll
      for (int m=0;m<4;m++)
        #pragma unroll
        for (int n=0;n<4;n++)
          asm("v_mfma_f32_16x16x32_bf16 %0, %1, %2, %0"
              : "+v"(acc[m][n]) : "v"(av[m]), "v"(bv[n]));
      __syncthreads();
      cur ^= 1;
    }
  }

  #pragma unroll
  for (int m=0;m<4;m++)
    #pragma unroll
    for (int n=0;n<4;n++)
      asm volatile("s_nop 7\n\ts_nop 7" : "+v"(acc[m][n]) ::);

  const long rbase = (EXPERT && OUT_SLOT) ? (long)(off0 + row0) : (long)row0;
  #pragma unroll
  for (int m=0;m<4;m++) {
    #pragma unroll
    for (int n=0;n<4;n++) {
      #pragma unroll
      for (int j=0;j<4;j++) {
        const long r = rbase + wm*64 + m*16 + fg*4 + j;
        const long c = col0 + wn*64 + n*16 + fr;
        const size_t ci = (size_t)coff + (size_t)r*ldc + c;
        float v = acc[m][n][j];
        if constexpr (EPI==0) {
          ((bf16*)Cout)[ci] = __float2bfloat16(v + bias[bofs + c]);
        } else if constexpr (EPI==1) {
          ((bf16*)Cout)[ci] = __float2bfloat16(v*scale);
        } else if constexpr (EPI==2) {
          ((float*)Cout)[ci] = v + bias[bofs + c] + res[(size_t)r*ldc + c];
        } else if constexpr (EPI==3) {
          const float t = v + bias[bofs + c];
          ((bf16*)Cout)[ci] = __float2bfloat16(0.5f*t*(1.0f+erff(t*0.70710678118654752f)));
        } else {
          const float t = v + bias[bofs + c];
          ((bf16*)Cout)[ci] = __float2bfloat16(t);
          Cf[ci] = t;
        }
      }
    }
  }
}

// ---------------------------------------------------------------------------
// Fused flash attention: one block = 64 Q-rows of one (b,h). 4 waves, each
// owns 16 Q-rows. K/V^T tiles staged via gload_lds with pre-swizzled source
// (XOR byte^=((row&7)<<4)); swizzled ds_read_b128 fragment reads.
// Online softmax fully in-register (row = fg*4+j is thread-local).
// ---------------------------------------------------------------------------
__global__ __launch_bounds__(256)
void k_flash(const bf16* __restrict__ qb, const bf16* __restrict__ kb,
             const bf16* __restrict__ vt, const int* __restrict__ mask,
             bf16* __restrict__ aob)
{
  const int qt = blockIdx.x, h = blockIdx.y, b = blockIdx.z;
  const int tid = threadIdx.x, wid = tid>>6, lane = tid&63;
  const int fr = lane & 15, fg = lane >> 4;
  __shared__ __align__(16) bf16 Ks[64*64];
  __shared__ __align__(16) bf16 Vs[64*64];
  __shared__ __align__(16) bf16 Pl[4][16*64];
  const int q0 = qt*64;
  const int qrow = q0 + wid*16 + fr;
  i32x4 qreg[2];
  #pragma unroll
  for (int c=0;c<2;c++)
    qreg[c] = *(const i32x4*)&qb[((size_t)(b*SS)+qrow)*DM + h*64 + c*32 + fg*8];
  f32x4 oacc[4];
  #pragma unroll
  for (int n=0;n<4;n++) oacc[n]=(f32x4)(0.f);
  float mrow[4], lrow[4];
  #pragma unroll
  for (int j=0;j<4;j++){ mrow[j]=-1e30f; lrow[j]=0.f; }

  const int srow = lane>>3;                 // 0..7 within 8-row chunk
  const int scolsw = ((lane&7) ^ srow)*8;   // pre-swizzled source column (elems)
  // swizzled fragment byte offsets (row-major 128B rows, byte ^= (row&7)<<4)
  auto swz = [](int row, int coleb)->int {  // coleb: byte offset within row
    return row*128 + (coleb ^ ((row&7)<<4));
  };

  for (int kt=0; kt<SS/64; kt++) {
    const int kv0 = kt*64;
    #pragma unroll
    for (int i=0;i<2;i++) {
      const int r = (wid*2+i)*8 + srow;
      stage16(kb + ((size_t)(b*SS)+kv0+r)*DM + h*64 + scolsw, (void*)&Ks[(wid*2+i)*512]);
      stage16(vt + ((size_t)(b*HH+h)*64 + r)*SS + kv0 + scolsw, (void*)&Vs[(wid*2+i)*512]);
    }
    __syncthreads();
    // ---- QK^T ----
    f32x4 sacc[4];
    #pragma unroll
    for (int n=0;n<4;n++) sacc[n]=(f32x4)(0.f);
    asm volatile("s_nop 1" ::);
    #pragma unroll
    for (int c=0;c<2;c++) {
      i32x4 bk[4];
      #pragma unroll
      for (int n=0;n<4;n++)
        bk[n] = *(const i32x4*)((const char*)Ks + swz(n*16+fr, c*64+fg*16));
      #pragma unroll
      for (int n=0;n<4;n++)
        asm("v_mfma_f32_16x16x32_bf16 %0, %1, %2, %0"
            : "+v"(sacc[n]) : "v"(qreg[c]), "v"(bk[n]));
    }
    #pragma unroll
    for (int n=0;n<4;n++)
      asm volatile("s_nop 7\n\ts_nop 7" : "+v"(sacc[n]) ::);
    // ---- mask + scale ----
    float sc[4][4];
    #pragma unroll
    for (int n=0;n<4;n++) {
      const bool mm = mask[b*SS + kv0 + n*16 + fr] != 0;
      #pragma unroll
      for (int j=0;j<4;j++)
        sc[n][j] = mm ? sacc[n][j]*0.125f : -1e30f;
    }
    // ---- online softmax (row = fg*4+j; reduce over fr group) ----
    float scale[4];
    #pragma unroll
    for (int j=0;j<4;j++) {
      float tm = fmaxf(fmaxf(sc[0][j],sc[1][j]),fmaxf(sc[2][j],sc[3][j]));
      #pragma unroll
      for (int o=8;o;o>>=1) tm = fmaxf(tm, __shfl_xor(tm,o));
      const float nm = fmaxf(mrow[j], tm);
      scale[j] = __expf(mrow[j]-nm);
      mrow[j] = nm;
      float ts = 0.f;
      #pragma unroll
      for (int n=0;n<4;n++) { sc[n][j] = __expf(sc[n][j]-nm); ts += sc[n][j]; }
      #pragma unroll
      for (int o=8;o;o>>=1) ts += __shfl_xor(ts,o);
      lrow[j] = lrow[j]*scale[j] + ts;
    }
    // ---- rescale O (fence: oacc last written by MFMA in prior tile) ----
    #pragma unroll
    for (int n=0;n<4;n++)
      asm volatile("s_nop 7\n\ts_nop 7" : "+v"(oacc[n]) ::);
    #pragma unroll
    for (int n=0;n<4;n++)
      #pragma unroll
      for (int j=0;j<4;j++) oacc[n][j] *= scale[j];
    // ---- write P (swizzled, wave-local region) ----
    char* plw = (char*)Pl[wid];
    #pragma unroll
    for (int n=0;n<4;n++)
      #pragma unroll
      for (int j=0;j<4;j++) {
        const int row = fg*4+j, col = n*16+fr;
        *(bf16*)(plw + row*128 + ((col*2) ^ ((row&7)<<4))) = __float2bfloat16(sc[n][j]);
      }
    // ---- PV ----
    asm volatile("s_nop 1" ::);
    #pragma unroll
    for (int c=0;c<2;c++) {
      i32x4 pa = *(const i32x4*)(plw + swz(fr, c*64+fg*16));
      i32x4 bv[4];
      #pragma unroll
      for (int n=0;n<4;n++)
        bv[n] = *(const i32x4*)((const char*)Vs + swz(n*16+fr, c*64+fg*16));
      #pragma unroll
      for (int n=0;n<4;n++)
        asm("v_mfma_f32_16x16x32_bf16 %0, %1, %2, %0"
            : "+v"(oacc[n]) : "v"(pa), "v"(bv[n]));
    }
    __syncthreads();
  }
  #pragma unroll
  for (int n=0;n<4;n++)
    asm volatile("s_nop 7\n\ts_nop 7" : "+v"(oacc[n]) ::);
  #pragma unroll
  for (int j=0;j<4;j++) {
    const float ri = 1.0f / lrow[j];
    const size_t rbase = ((size_t)(b*SS) + q0 + wid*16 + fg*4 + j)*DM + h*64;
    #pragma unroll
    for (int n=0;n<4;n++)
      aob[rbase + n*16 + fr] = __float2bfloat16(oacc[n][j] * ri);
  }
}

// ---------------------------------------------------------------------------
// Transpose + convert to bf16, vectorized (weights)
// ---------------------------------------------------------------------------
template<typename T>
__global__ __launch_bounds__(256)
void et_transpose(const T* __restrict__ in, bf16* __restrict__ outp,
                  int ldin, int ldout, long in_bs, long out_bs)
{
  __shared__ float tile[64][65];
  const int z = blockIdx.z;
  in   += (size_t)z * in_bs;
  outp += (size_t)z * out_bs;
  const int r0 = blockIdx.x*64, c0 = blockIdx.y*64;
  const int tid = threadIdx.x;
  #pragma unroll
  for (int i=0;i<4;i++) {
    const int idx = tid*4 + i*1024;
    const int r = idx>>6, c = idx&63;
    if constexpr (sizeof(T)==4) {
      const float4 v = *(const float4*)&in[(size_t)(r0+r)*ldin + c0 + c];
      tile[r][c]=v.x; tile[r][c+1]=v.y; tile[r][c+2]=v.z; tile[r][c+3]=v.w;
    } else {
      const ushort4 v = *(const ushort4*)&in[(size_t)(r0+r)*ldin + c0 + c];
      tile[r][c]=bf2f(v.x); tile[r][c+1]=bf2f(v.y); tile[r][c+2]=bf2f(v.z); tile[r][c+3]=bf2f(v.w);
    }
  }
  __syncthreads();
  #pragma unroll
  for (int i=0;i<4;i++) {
    const int idx = tid*4 + i*1024;
    const int c = idx>>6, r = idx&63;
    ushort4 o;
    o.x=f2bf(tile[r][c]); o.y=f2bf(tile[r+1][c]); o.z=f2bf(tile[r+2][c]); o.w=f2bf(tile[r+3][c]);
    *(ushort4*)&outp[(size_t)(c0+c)*ldout + r0 + r] = o;
  }
}

// Per-(b,h) head-slice transpose: in [S, 64] slice of [*, DM] -> out [64][S].
template<typename TI, typename TO>
__global__ __launch_bounds__(256)
void k_trans_head(const TI* __restrict__ in, TO* __restrict__ outp)
{
  __shared__ float tile[64][65];
  const int z = blockIdx.z;
  in   += (size_t)(z>>4)*SS*DM + (size_t)(z&15)*64;
  outp += (size_t)z*DHD*SS;
  const int r0 = blockIdx.x*64;
  const int tid = threadIdx.x;
  #pragma unroll
  for (int i=0;i<4;i++) {
    const int idx = tid*4 + i*1024;
    const int r = idx>>6, c = idx&63;
    if constexpr (sizeof(TI)==4) {
      const float4 v = *(const float4*)&in[(size_t)(r0+r)*DM + c];
      tile[r][c]=v.x; tile[r][c+1]=v.y; tile[r][c+2]=v.z; tile[r][c+3]=v.w;
    } else {
      const ushort4 v = *(const ushort4*)&in[(size_t)(r0+r)*DM + c];
      tile[r][c]=bf2f(v.x); tile[r][c+1]=bf2f(v.y); tile[r][c+2]=bf2f(v.z); tile[r][c+3]=bf2f(v.w);
    }
  }
  __syncthreads();
  #pragma unroll
  for (int i=0;i<4;i++) {
    const int idx = tid*4 + i*1024;
    const int c = idx>>6, r = idx&63;
    if constexpr (sizeof(TO)==4) {
      float4 o;
      o.x=tile[r][c]; o.y=tile[r+1][c]; o.z=tile[r+2][c]; o.w=tile[r+3][c];
      *(float4*)&outp[(size_t)c*SS + r0 + r] = o;
    } else {
      ushort4 o;
      o.x=f2bf(tile[r][c]); o.y=f2bf(tile[r+1][c]); o.z=f2bf(tile[r+2][c]); o.w=f2bf(tile[r+3][c]);
      *(ushort4*)&outp[(size_t)c*SS + r0 + r] = o;
    }
  }
}

// Transpose f32 -> 2-term split bf16 planes; z selects {wq,wk,wv}
__global__ __launch_bounds__(256)
void et_transpose2(const float* __restrict__ in0, const float* __restrict__ in1,
                   const float* __restrict__ in2, bf16* __restrict__ outp,
                   int ldin, int ldout, long pstride, long out_zs)
{
  __shared__ float tile[64][65];
  const int z = blockIdx.z;
  const float* in = (z==0) ? in0 : (z==1) ? in1 : in2;
  outp += (size_t)z * out_zs;
  const int r0 = blockIdx.x*64, c0 = blockIdx.y*64;
  const int tid = threadIdx.x;
  #pragma unroll
  for (int i=0;i<4;i++) {
    const int idx = tid*4 + i*1024;
    const int r = idx>>6, c = idx&63;
    const float4 v = *(const float4*)&in[(size_t)(r0+r)*ldin + c0 + c];
    tile[r][c]=v.x; tile[r][c+1]=v.y; tile[r][c+2]=v.z; tile[r][c+3]=v.w;
  }
  __syncthreads();
  #pragma unroll
  for (int i=0;i<4;i++) {
    const int idx = tid*4 + i*1024;
    const int c = idx>>6, r = idx&63;
    ushort4 o0, o1;
    unsigned short* p0 = (unsigned short*)&o0;
    unsigned short* p1 = (unsigned short*)&o1;
    #pragma unroll
    for (int j=0;j<4;j++) {
      float v = tile[r+j][c];
      const unsigned short h0 = f2bf(v);
      p0[j] = h0;
      v -= bf2f(h0);
      p1[j] = f2bf(v);
    }
    const size_t oi = (size_t)(c0+c)*ldout + r0 + r;
    *(ushort4*)&outp[oi] = o0;
    *(ushort4*)&outp[oi + pstride] = o1;
  }
}

// ---------------------------------------------------------------------------
// LayerNorm -> 2-term split bf16 planes (LN1)
// ---------------------------------------------------------------------------
__global__ __launch_bounds__(256)
void et_ln2(const float* __restrict__ xin, const float* __restrict__ g,
            const float* __restrict__ bsh, bf16* __restrict__ outp, long pstride)
{
  const int row = blockIdx.x, tid = threadIdx.x;
  const float4 v = ((const float4*)(xin + (size_t)row*DM))[tid];
  float s = v.x+v.y+v.z+v.w;
  #pragma unroll
  for (int o=32;o;o>>=1) s += __shfl_xor(s,o);
  __shared__ float s4[4], q4[4];
  if ((tid&63)==0) s4[tid>>6]=s;
  __syncthreads();
  const float mu = (s4[0]+s4[1]+s4[2]+s4[3]) * (1.f/DM);
  const float d0=v.x-mu,d1=v.y-mu,d2=v.z-mu,d3=v.w-mu;
  float q = d0*d0+d1*d1+d2*d2+d3*d3;
  #pragma unroll
  for (int o=32;o;o>>=1) q += __shfl_xor(q,o);
  if ((tid&63)==0) q4[tid>>6]=q;
  __syncthreads();
  const float var = (q4[0]+q4[1]+q4[2]+q4[3]) * (1.f/DM);
  const float rstd = rsqrtf(var + 1e-5f);
  const float4 gg = ((const float4*)g)[tid];
  const float4 bb = ((const float4*)bsh)[tid];
  float of[4];
  of[0] = d0*rstd*gg.x + bb.x;
  of[1] = d1*rstd*gg.y + bb.y;
  of[2] = d2*rstd*gg.z + bb.z;
  of[3] = d3*rstd*gg.w + bb.w;
  ushort4 p0, p1;
  unsigned short* pp0 = (unsigned short*)&p0;
  unsigned short* pp1 = (unsigned short*)&p1;
  #pragma unroll
  for (int k=0;k<4;k++) {
    float vv = of[k];
    const unsigned short h0 = f2bf(vv); pp0[k] = h0;
    vv -= bf2f(h0);
    pp1[k] = f2bf(vv);
  }
  const size_t oi = (size_t)row*DM;
  ((ushort4*)(outp + oi))[tid] = p0;
  ((ushort4*)(outp + pstride + oi))[tid] = p1;
}

// ---------------------------------------------------------------------------
// Router fused on x1: LN2 (f32) + write xn2 bf16 + logits + top-2 +
// flag near-ties into per-batch buckets flaglist[b*1024+ib], counts cntb[b].
// ---------------------------------------------------------------------------
__global__ __launch_bounds__(256)
void et_router2(const float* __restrict__ x1, const float* __restrict__ g,
                const float* __restrict__ bsh, const float* __restrict__ wr,
                const float* __restrict__ br, bf16* __restrict__ xn2,
                int* __restrict__ t2e, float* __restrict__ t2p,
                int* __restrict__ flaglist, int* __restrict__ cntb)
{
  const int wid = threadIdx.x>>6, lane = threadIdx.x&63;
  const int t = blockIdx.x*4 + wid;
  const float* xr = x1 + (size_t)t*DM;
  float4 xv[4];
  float s = 0.f;
  #pragma unroll
  for (int p=0;p<4;p++){
    xv[p] = *(const float4*)&xr[p*256 + lane*4];
    s += xv[p].x+xv[p].y+xv[p].z+xv[p].w;
  }
  #pragma unroll
  for (int o=32;o;o>>=1) s += __shfl_xor(s,o);
  const float mu = s * (1.f/DM);
  float q = 0.f;
  #pragma unroll
  for (int p=0;p<4;p++){
    const float a=xv[p].x-mu,b=xv[p].y-mu,c=xv[p].z-mu,d=xv[p].w-mu;
    q += a*a+b*b+c*c+d*d;
  }
  #pragma unroll
  for (int o=32;o;o>>=1) q += __shfl_xor(q,o);
  const float rstd = rsqrtf(q*(1.f/DM) + 1e-5f);
  float acc[NEXP];
  #pragma unroll
  for (int e=0;e<NEXP;e++) acc[e]=0.f;
  #pragma unroll
  for (int p=0;p<4;p++){
    const int d0 = p*256 + lane*4;
    const float4 gg = *(const float4*)&g[d0];
    const float4 bb = *(const float4*)&bsh[d0];
    float xn[4];
    xn[0]=(xv[p].x-mu)*rstd*gg.x+bb.x;
    xn[1]=(xv[p].y-mu)*rstd*gg.y+bb.y;
    xn[2]=(xv[p].z-mu)*rstd*gg.z+bb.z;
    xn[3]=(xv[p].w-mu)*rstd*gg.w+bb.w;
    ushort4 xo;
    xo.x=f2bf(xn[0]); xo.y=f2bf(xn[1]); xo.z=f2bf(xn[2]); xo.w=f2bf(xn[3]);
    *(ushort4*)&xn2[(size_t)t*DM + d0] = xo;
    #pragma unroll
    for (int j=0;j<4;j++){
      const float4 w0  = ((const float4*)&wr[(size_t)(d0+j)*NEXP])[0];
      const float4 w1v = ((const float4*)&wr[(size_t)(d0+j)*NEXP])[1];
      acc[0]+=xn[j]*w0.x;  acc[1]+=xn[j]*w0.y;  acc[2]+=xn[j]*w0.z;  acc[3]+=xn[j]*w0.w;
      acc[4]+=xn[j]*w1v.x; acc[5]+=xn[j]*w1v.y; acc[6]+=xn[j]*w1v.z; acc[7]+=xn[j]*w1v.w;
    }
  }
  #pragma unroll
  for (int e=0;e<NEXP;e++)
    #pragma unroll
    for (int o=32;o;o>>=1) acc[e] += __shfl_xor(acc[e],o);
  if (lane==0) {
    float v0=-1e30f, v1=-1e30f, v2=-1e30f; int e0=0, e1=0;
    #pragma unroll
    for (int e=0;e<NEXP;e++) {
      const float v = acc[e] + br[e];
      if (v>v0){v2=v1;v1=v0;e1=e0;v0=v;e0=e;}
      else if (v>v1){v2=v1;v1=v;e1=e;}
      else if (v>v2){v2=v;}
    }
    const float dd = __expf(v1-v0);
    const float p0 = 1.f/(1.f+dd);
    t2e[t*2]=e0; t2e[t*2+1]=e1;
    t2p[t*2]=p0; t2p[t*2+1]=dd*p0;
    if (v1 - v2 < 0.02f) {
      const int b = t >> 10;
      const int ib = atomicAdd(&cntb[b], 1);
      flaglist[b*1024 + ib] = t;
    }
  }
}

// ---------------------------------------------------------------------------
// Exact f32 attention recompute, 4 tokens per block iteration.
// ---------------------------------------------------------------------------
__global__ __launch_bounds__(256)
void k_rec4(const float* __restrict__ qf, const float* __restrict__ kfT,
            const float* __restrict__ vf, const int* __restrict__ flaglist,
            const int* __restrict__ cntb, const int* __restrict__ mask,
            float* __restrict__ aoF)
{
  const int h = blockIdx.y, b = blockIdx.z;
  const int tid = threadIdx.x, lane = tid&63, wv_ = tid>>6;
  const int nb = cntb[b];
  __shared__ float qs[4][64];
  __shared__ float scb[4][SS];
  __shared__ float part[4][4][64];
  __shared__ float tsum[4];
  const int* mrow = mask + (size_t)b*SS;
  const float* kbase = kfT + ((size_t)(b*HH + h)*DHD)*SS + tid;
  const float* vbase = vf + (size_t)b*SS*DM + h*64 + lane;

  for (int t0 = blockIdx.x*4; t0 < nb; t0 += gridDim.x*4) {
    const int nt = min(4, nb - t0);
    for (int idx = tid; idx < 4*64; idx += 256) {
      const int j = idx >> 6, d = idx & 63;
      float qv = 0.f;
      if (j < nt) {
        const int t = flaglist[b*1024 + t0 + j];
        qv = qf[(size_t)t*DM + h*64 + d];
      }
      qs[j][d] = qv;
    }
    __syncthreads();
    float a00=0,a01=0,a02=0,a03=0, a10=0,a11=0,a12=0,a13=0;
    float a20=0,a21=0,a22=0,a23=0, a30=0,a31=0,a32=0,a33=0;
    #pragma unroll 4
    for (int u=0; u<64; u++) {
      const float* kr = kbase + (size_t)u*SS;
      const float k0 = kr[0], k1 = kr[256], k2 = kr[512], k3 = kr[768];
      const float q0 = qs[0][u], q1 = qs[1][u], q2 = qs[2][u], q3 = qs[3][u];
      a00 += q0*k0; a01 += q0*k1; a02 += q0*k2; a03 += q0*k3;
      a10 += q1*k0; a11 += q1*k1; a12 += q1*k2; a13 += q1*k3;
      a20 += q2*k0; a21 += q2*k1; a22 += q2*k2; a23 += q2*k3;
      a30 += q3*k0; a31 += q3*k1; a32 += q3*k2; a33 += q3*k3;
    }
    const bool m0 = mrow[tid]!=0, m1 = mrow[tid+256]!=0, m2 = mrow[tid+512]!=0, m3 = mrow[tid+768]!=0;
    scb[0][tid]=m0?a00*0.125f:-1e30f; scb[0][tid+256]=m1?a01*0.125f:-1e30f;
    scb[0][tid+512]=m2?a02*0.125f:-1e30f; scb[0][tid+768]=m3?a03*0.125f:-1e30f;
    scb[1][tid]=m0?a10*0.125f:-1e30f; scb[1][tid+256]=m1?a11*0.125f:-1e30f;
    scb[1][tid+512]=m2?a12*0.125f:-1e30f; scb[1][tid+768]=m3?a13*0.125f:-1e30f;
    scb[2][tid]=m0?a20*0.125f:-1e30f; scb[2][tid+256]=m1?a21*0.125f:-1e30f;
    scb[2][tid+512]=m2?a22*0.125f:-1e30f; scb[2][tid+768]=m3?a23*0.125f:-1e30f;
    scb[3][tid]=m0?a30*0.125f:-1e30f; scb[3][tid+256]=m1?a31*0.125f:-1e30f;
    scb[3][tid+512]=m2?a32*0.125f:-1e30f; scb[3][tid+768]=m3?a33*0.125f:-1e30f;
    __syncthreads();
    {
      const int j = wv_;
      float v[16];
      float lm = -1e30f;
      #pragma unroll
      for (int kk=0;kk<16;kk++) { v[kk] = scb[j][lane + kk*64]; lm = fmaxf(lm, v[kk]); }
      #pragma unroll
      for (int o=32;o;o>>=1) lm = fmaxf(lm, __shfl_xor(lm,o));
      float ls = 0.f;
      #pragma unroll
      for (int kk=0;kk<16;kk++) {
        const float e = expf(v[kk]-lm);
        scb[j][lane + kk*64] = e; ls += e;
      }
      #pragma unroll
      for (int o=32;o;o>>=1) ls += __shfl_xor(ls,o);
      if (lane==0) tsum[j] = ls;
    }
    __syncthreads();
    float p0=0.f, p1=0.f, p2=0.f, p3=0.f;
    for (int s = wv_*4; s < SS; s += 16) {
      const float v0 = vbase[(size_t) s   *DM];
      const float v1 = vbase[(size_t)(s+1)*DM];
      const float v2 = vbase[(size_t)(s+2)*DM];
      const float v3 = vbase[(size_t)(s+3)*DM];
      p0 += scb[0][s]*v0 + scb[0][s+1]*v1 + scb[0][s+2]*v2 + scb[0][s+3]*v3;
      p1 += scb[1][s]*v0 + scb[1][s+1]*v1 + scb[1][s+2]*v2 + scb[1][s+3]*v3;
      p2 += scb[2][s]*v0 + scb[2][s+1]*v1 + scb[2][s+2]*v2 + scb[2][s+3]*v3;
      p3 += scb[3][s]*v0 + scb[3][s+1]*v1 + scb[3][s+2]*v2 + scb[3][s+3]*v3;
    }
    part[wv_][0][lane] = p0;
    part[wv_][1][lane] = p1;
    part[wv_][2][lane] = p2;
    part[wv_][3][lane] = p3;
    __syncthreads();
    for (int idx = tid; idx < nt*64; idx += 256) {
      const int j = idx >> 6, d = idx & 63;
      aoF[(size_t)(b*1024 + t0 + j)*DM + h*64 + d] =
        (part[0][j][d]+part[1][j][d]+part[2][j][d]+part[3][j][d]) / tsum[j];
    }
    __syncthreads();
  }
}

// ---------------------------------------------------------------------------
// Tiled flagged out-proj: 8 tokens x 128 cols per block; wo reuse x8.
// ---------------------------------------------------------------------------
__global__ __launch_bounds__(256)
void k_flag_proj2(const float* __restrict__ aoF, const float* __restrict__ wo,
                  const float* __restrict__ bo, const float* __restrict__ x,
                  const int* __restrict__ flaglist, const int* __restrict__ cntb,
                  float* __restrict__ yF)
{
  const int tile = blockIdx.x;
  const int b = tile >> 7;
  const int i0 = (tile & 127) * 8;
  const int nb = cntb[b];
  if (i0 >= nb) return;
  const int nt = min(8, nb - i0);
  const int c0 = blockIdx.y * 128;
  const int tid = threadIdx.x;
  const int c = c0 + (tid & 127);
  const int dh = tid >> 7;
  __shared__ float ar[8][DM];
  __shared__ float ph[2][8][128];
  for (int k = tid; k < 8*256; k += 256) {
    const int j = k >> 8, q4i = k & 255;
    float4 v = make_float4(0.f,0.f,0.f,0.f);
    if (j < nt) v = ((const float4*)(aoF + (size_t)(b*1024 + i0 + j)*DM))[q4i];
    ((float4*)ar[j])[q4i] = v;
  }
  __syncthreads();
  float acc0=0.f, acc1=0.f, acc2=0.f, acc3=0.f;
  float acc4=0.f, acc5=0.f, acc6=0.f, acc7=0.f;
  const int dbase = dh*512;
  #pragma unroll 4
  for (int d=0; d<512; d++) {
    const float w = wo[(size_t)(dbase+d)*DM + c];
    acc0 += ar[0][dbase+d]*w; acc1 += ar[1][dbase+d]*w;
    acc2 += ar[2][dbase+d]*w; acc3 += ar[3][dbase+d]*w;
    acc4 += ar[4][dbase+d]*w; acc5 += ar[5][dbase+d]*w;
    acc6 += ar[6][dbase+d]*w; acc7 += ar[7][dbase+d]*w;
  }
  const int lc = tid & 127;
  ph[dh][0][lc]=acc0; ph[dh][1][lc]=acc1; ph[dh][2][lc]=acc2; ph[dh][3][lc]=acc3;
  ph[dh][4][lc]=acc4; ph[dh][5][lc]=acc5; ph[dh][6][lc]=acc6; ph[dh][7][lc]=acc7;
  __syncthreads();
  for (int k = tid; k < nt*128; k += 256) {
    const int j = k >> 7, ccl = k & 127;
    const int cc = c0 + ccl;
    const int slot = b*1024 + i0 + j;
    const int t = flaglist[slot];
    yF[(size_t)slot*DM + cc] = ph[0][j][ccl] + ph[1][j][ccl] + bo[cc] + x[(size_t)t*DM + cc];
  }
}

// ---------------------------------------------------------------------------
// Flagged LN + router: overwrite t2e/t2p with exact selection (slot-indexed)
// ---------------------------------------------------------------------------
__global__ __launch_bounds__(256)
void k_flag_router(const float* __restrict__ yF, const float* __restrict__ g,
                   const float* __restrict__ bsh, const float* __restrict__ wr,
                   const float* __restrict__ br, const int* __restrict__ flaglist,
                   const int* __restrict__ cntb, int* __restrict__ t2e,
                   float* __restrict__ t2p)
{
  const int tid = threadIdx.x, lane = tid&63, wv_ = tid>>6;
  __shared__ float s4[4], q4[4], pt[4][8];
  for (int idx = blockIdx.x; idx < NTOK; idx += gridDim.x) {
    const int b = idx >> 10, ib = idx & 1023;
    if (ib >= cntb[b]) continue;
    const int t = flaglist[idx];
    const float4 v = ((const float4*)(yF + (size_t)idx*DM))[tid];
    float s = v.x+v.y+v.z+v.w;
    #pragma unroll
    for (int o=32;o;o>>=1) s += __shfl_xor(s,o);
    if (lane==0) s4[wv_]=s;
    __syncthreads();
    const float mu = (s4[0]+s4[1]+s4[2]+s4[3])*(1.f/DM);
    const float d0=v.x-mu, d1=v.y-mu, d2=v.z-mu, d3=v.w-mu;
    float q = d0*d0+d1*d1+d2*d2+d3*d3;
    #pragma unroll
    for (int o=32;o;o>>=1) q += __shfl_xor(q,o);
    if (lane==0) q4[wv_]=q;
    __syncthreads();
    const float var = (q4[0]+q4[1]+q4[2]+q4[3])*(1.f/DM);
    const float rstd = 1.0f/sqrtf(var + 1e-5f);
    const int dbase = tid*4;
    const float4 gg = ((const float4*)g)[tid];
    const float4 bb = ((const float4*)bsh)[tid];
    const float x0 = d0*rstd*gg.x+bb.x, x1_ = d1*rstd*gg.y+bb.y;
    const float x2 = d2*rstd*gg.z+bb.z, x3_ = d3*rstd*gg.w+bb.w;
    float pl[8];
    #pragma unroll
    for (int e=0;e<8;e++)
      pl[e] = x0*wr[(size_t)(dbase+0)*8+e] + x1_*wr[(size_t)(dbase+1)*8+e]
            + x2*wr[(size_t)(dbase+2)*8+e] + x3_*wr[(size_t)(dbase+3)*8+e];
    #pragma unroll
    for (int e=0;e<8;e++)
      #pragma unroll
      for (int o=32;o;o>>=1) pl[e] += __shfl_xor(pl[e],o);
    if (lane==0) {
      #pragma unroll
      for (int e=0;e<8;e++) pt[wv_][e]=pl[e];
    }
    __syncthreads();
    if (tid==0) {
      float v0=-1e30f, v1=-1e30f; int e0=0, e1=0;
      for (int e=0;e<8;e++) {
        const float L = pt[0][e]+pt[1][e]+pt[2][e]+pt[3][e] + br[e];
        if (L>v0){v1=v0;e1=e0;v0=L;e0=e;}
        else if (L>v1){v1=L;e1=e;}
      }
      const float dd=expf(v1-v0), p0=1.f/(1.f+dd);
      t2e[t*2]=e0; t2e[t*2+1]=e1;
      t2p[t*2]=p0; t2p[t*2+1]=dd*p0;
    }
    __syncthreads();
  }
}

__global__ void et_init(const float* __restrict__ bq, const float* __restrict__ bk,
                        const float* __restrict__ bv, float* __restrict__ bcat,
                        int* __restrict__ cnt)
{
  const int i = blockIdx.x*256 + threadIdx.x;
  if (i < 16) cnt[i]=0;
  if (i < DM) { bcat[i]=bq[i]; bcat[DM+i]=bk[i]; bcat[2*DM+i]=bv[i]; }
}

__global__ void et_count(const int* __restrict__ t2e, int* __restrict__ cnt)
{
  const int t = blockIdx.x*256 + threadIdx.x;
  if (t < NTOK) {
    atomicAdd(&cnt[t2e[t*2]], 1);
    atomicAdd(&cnt[t2e[t*2+1]], 1);
  }
}

__global__ void et_scan(const int* __restrict__ cnt, int* __restrict__ poff,
                        int* __restrict__ fil, int* __restrict__ slots)
{
  const int tid = threadIdx.x;
  if (tid==0) {
    int o=0;
    for (int e=0;e<NEXP;e++){ poff[e]=o; o += ((cnt[e]+127)>>7)<<7; }
    poff[NEXP]=o;
  }
  if (tid<NEXP) fil[tid]=0;
  for (int i=tid;i<CAP;i+=256) slots[i]=0;
}

__global__ void et_fill(const int* __restrict__ t2e, const int* __restrict__ poff,
                        int* __restrict__ fil, int* __restrict__ slots, int* __restrict__ sof)
{
  const int t = blockIdx.x*256 + threadIdx.x;
  if (t >= NTOK) return;
  #pragma unroll
  for (int kk=0;kk<2;kk++) {
    const int e = t2e[t*2+kk];
    const int pos = atomicAdd(&fil[e], 1);
    const int sl = poff[e] + pos;
    slots[sl] = t;
    sof[t*2+kk] = sl;
  }
}

__global__ __launch_bounds__(256)
void et_combine(const float* __restrict__ x1, const bf16* __restrict__ eo,
                const float* __restrict__ t2p, const int* __restrict__ sof,
                float* __restrict__ outp)
{
  const int t = blockIdx.x, tid = threadIdx.x;
  const int s0 = sof[t*2], s1 = sof[t*2+1];
  const float p0 = t2p[t*2], p1 = t2p[t*2+1];
  const float4 xv = ((const float4*)(x1 + (size_t)t*DM))[tid];
  const ushort4 a = ((const ushort4*)(eo + (size_t)s0*DM))[tid];
  const ushort4 c = ((const ushort4*)(eo + (size_t)s1*DM))[tid];
  float4 o;
  o.x = xv.x + p0*bf2f(a.x) + p1*bf2f(c.x);
  o.y = xv.y + p0*bf2f(a.y) + p1*bf2f(c.y);
  o.z = xv.z + p0*bf2f(a.z) + p1*bf2f(c.z);
  o.w = xv.w + p0*bf2f(a.w) + p1*bf2f(c.w);
  ((float4*)(outp + (size_t)t*DM))[tid] = o;
}

// ---------------------------------------------------------------------------
extern "C" void kernel_launch(void* const* d_in, const int* in_sizes, int n_in,
                              void* d_out, int out_size, void* d_ws, size_t ws_size,
                              hipStream_t stream)
{
  (void)in_sizes; (void)n_in; (void)out_size; (void)ws_size;
  const float* x    = (const float*)d_in[0];
  const int*   mask = (const int*)  d_in[1];
  const float* ln1g = (const float*)d_in[2];
  const float* ln1b = (const float*)d_in[3];
  const float* ln2g = (const float*)d_in[4];
  const float* ln2b = (const float*)d_in[5];
  const float* wq   = (const float*)d_in[6];
  const float* bq   = (const float*)d_in[7];
  const float* wk   = (const float*)d_in[8];
  const float* bk   = (const float*)d_in[9];
  const float* wv   = (const float*)d_in[10];
  const float* bv   = (const float*)d_in[11];
  const float* wo   = (const float*)d_in[12];
  const float* bo   = (const float*)d_in[13];
  const float* wr   = (const float*)d_in[14];
  const float* br   = (const float*)d_in[15];
  const float* w1   = (const float*)d_in[16];
  const float* b1   = (const float*)d_in[17];
  const float* w2   = (const float*)d_in[18];
  const float* b2   = (const float*)d_in[19];
  float* outp = (float*)d_out;

  char* wsb = (char*)d_ws;
  size_t off = 0;
  auto alloc = [&](size_t bytes)->void* {
    void* p = wsb + off;
    off += (bytes + 255) & ~(size_t)255;
    return p;
  };
  const long WPS  = (long)DM*DM;
  const long XPS  = (long)NTOK*DM;
  const long EWS  = (long)DM*FFD;
  bf16*  wqT2  = (bf16*) alloc((size_t)2*WPS*2);
  bf16*  wkT2  = (bf16*) alloc((size_t)2*WPS*2);
  bf16*  wvT2  = (bf16*) alloc((size_t)2*WPS*2);
  bf16*  woT   = (bf16*) alloc((size_t)WPS*2);
  bf16*  w1Ta  = (bf16*) alloc((size_t)NEXP*EWS*2);   // 64 MB
  bf16*  w2Ta  = (bf16*) alloc((size_t)NEXP*EWS*2);   // 64 MB
  bf16*  xn2p  = (bf16*) alloc((size_t)2*XPS*2);
  bf16*  qb    = (bf16*) alloc((size_t)XPS*2);
  bf16*  kb    = (bf16*) alloc((size_t)XPS*2);
  bf16*  vb    = (bf16*) alloc((size_t)XPS*2);
  bf16*  vt    = (bf16*) alloc((size_t)XPS*2);
  float* qf    = (float*)alloc((size_t)XPS*4);
  float* kf    = (float*)alloc((size_t)XPS*4);
  float* vf    = (float*)alloc((size_t)XPS*4);
  float* kfT   = (float*)alloc((size_t)XPS*4);   // [b][h][64][S] f32
  bf16*  aob   = (bf16*) alloc((size_t)XPS*2);
  float* x1    = (float*)alloc((size_t)XPS*4);
  bf16*  xn2   = (bf16*) alloc((size_t)XPS*2);
  bf16*  hbuf  = (bf16*) alloc((size_t)CAP*FFD*2);
  bf16*  eo    = (bf16*) alloc((size_t)CAP*DM*2);
  float* bcat  = (float*)alloc((size_t)3*DM*4);
  int*   t2e   = (int*)  alloc((size_t)NTOK*2*4);
  float* t2p   = (float*)alloc((size_t)NTOK*2*4);
  int*   slots = (int*)  alloc((size_t)CAP*4);
  int*   sof   = (int*)  alloc((size_t)NTOK*2*4);
  int*   flagl = (int*)  alloc((size_t)NTOK*4);
  int*   cnt   = (int*)  alloc(64);
  int*   fil   = (int*)  alloc(64);
  int*   poff  = (int*)  alloc(64);
  int*   cntb  = cnt + 8;
  // Aliases (dead-buffer reuse):
  float* aoF   = (float*)qb;      // over qb+kb (dead after flash)
  float* yF    = (float*)vb;      // over vb+vt (dead after flash)

  const dim3 T256(256);

  et_init<<<4,T256,0,stream>>>(bq, bk, bv, bcat, cnt);
  et_transpose2<<<dim3(DM/64,DM/64,3),T256,0,stream>>>(wq, wk, wv, wqT2, DM, DM, WPS, 2*WPS);
  et_transpose<float><<<dim3(DM/64,DM/64,1),T256,0,stream>>>(wo, woT, DM, DM, 0, 0);

  et_ln2<<<NTOK,T256,0,stream>>>(x, ln1g, ln1b, xn2p, XPS);

  // QKV: fused 2-term split (both planes staged per K-step, 3 MFMA combos)
  et_gemm<128,64,4,false,false,false,3,0><<<dim3(NTOK/128, DM/64, 3),dim3(128),0,stream>>>(
      xn2p, wqT2, qb, bcat, nullptr, DM, DM, DM, DM,
      0, 2*WPS, XPS, 1.f, nullptr, nullptr, XPS, WPS, qf, DM);

  // head-slice transposes: V (bf16) and K (f32), z = b*16+h
  k_trans_head<bf16,bf16><<<dim3(SS/64,1,BB*HH),T256,0,stream>>>(vb, vt);
  k_trans_head<float,float><<<dim3(SS/64,1,BB*HH),T256,0,stream>>>(kf, kfT);

  // fused flash attention (replaces QK^T GEMM + softmax + PV GEMM)
  k_flash<<<dim3(SS/64, HH, BB),T256,0,stream>>>(qb, kb, vt, mask, aob);

  // x1 = x + (ao @ wo + bo): 64x64 tiles -> 1024 blocks
  et_gemm<64,64,2,false,false,false,1,0><<<dim3(NTOK/64, DM/64, 1),dim3(64),0,stream>>>(
      aob, woT, x1, bo, x, DM, DM, DM, DM, 0,0,0, 1.f, nullptr,nullptr, 0,0,nullptr, 0);

  // router (fused LN2 + xn2 write)
  et_router2<<<NTOK/4,T256,0,stream>>>(x1, ln2g, ln2b, wr, br, xn2, t2e, t2p, flagl, cntb);
  k_rec4<<<dim3(32,HH,BB),T256,0,stream>>>(qf, kfT, vf, flagl, cntb, mask, aoF);
  k_flag_proj2<<<dim3(NTOK/8, DM/128),T256,0,stream>>>(aoF, wo, bo, x, flagl, cntb, yF);
  k_flag_router<<<1024,T256,0,stream>>>(yF, ln2g, ln2b, wr, br, flagl, cntb, t2e, t2p);

  et_count<<<NTOK/256,T256,0,stream>>>(t2e, cnt);
  et_scan<<<1,T256,0,stream>>>(cnt, poff, fil, slots);
  et_fill<<<NTOK/256,T256,0,stream>>>(t2e, poff, fil, slots, sof);

  // expert weight transposes, z-batched
  et_transpose<float><<<dim3(DM/64, FFD/64, NEXP),T256,0,stream>>>(w1, w1Ta, FFD, DM, EWS, EWS);
  et_transpose<float><<<dim3(FFD/64, DM/64, NEXP),T256,0,stream>>>(w2, w2Ta, DM, FFD, EWS, EWS);

  // FF1 / FF2: both 128x128 (verified best tile for B-panel reuse)
  et_gemm<128,128,3,true,true,true,1,0><<<dim3(NTOK/128, FFD/128, NEXP),T256,0,stream>>>(
      xn2, w1Ta, hbuf, b1, nullptr, DM, DM, DM, FFD,
      0, EWS, 0, 1.f, poff, slots, 0,0,nullptr, FFD);
  et_gemm<128,128,0,true,false,true,1,0><<<dim3(NTOK/128, DM/128, NEXP),T256,0,stream>>>(
      hbuf, w2Ta, eo, b2, nullptr, FFD, FFD, FFD, DM,
      0, EWS, 0, 1.f, poff, nullptr, 0,0,nullptr, DM);

  et_combine<<<NTOK,T256,0,stream>>>(x1, eo, t2p, sof, outp);
}